// Round 1
// baseline (1084.273 us; speedup 1.0000x reference)
//
#include <hip/hip_runtime.h>
#include <hip/hip_bf16.h>
#include <cstdint>

#define NEG_SLOPE 0.2f

// ---------------------------------------------------------------------------
// int64-vs-int32 edge_index detection.
// If edge_index is int64 (little-endian, values in [0,100000)), every odd
// int32 word of the src row is the zero high-word. If int32, odd words are
// random node ids (P(all zero) ~ 0). Flag: 1 => int64, 0 => int32.
// ---------------------------------------------------------------------------
__global__ __launch_bounds__(256) void detect_kernel(const int* __restrict__ ei,
                                                     int* __restrict__ flag) {
    __shared__ int red[256];
    int t = threadIdx.x;
    int v = 0;
    for (int i = t; i < 2048; i += 256) v |= ei[2 * i + 1];
    red[t] = v;
    __syncthreads();
    for (int off = 128; off; off >>= 1) {
        if (t < off) red[t] |= red[t + off];
        __syncthreads();
    }
    if (t == 0) *flag = (red[0] == 0) ? 1 : 0;
}

__device__ inline int get_ei(const int* ei, int is64, long idx) {
    return is64 ? ei[2 * idx] : ei[(int)idx];
}

// ---------------------------------------------------------------------------
// CSR build: degree histogram -> exclusive scan -> scatter (src ids by dst).
// Edge i < E comes from edge_index; i in [E, E+N) is the self-loop (i-E).
// ---------------------------------------------------------------------------
__global__ __launch_bounds__(256) void count_kernel(const int* __restrict__ ei,
                                                    const int* __restrict__ flag,
                                                    int* __restrict__ deg, int E, int n) {
    int i = blockIdx.x * blockDim.x + threadIdx.x;
    int total = E + n;
    if (i >= total) return;
    int is64 = *flag;
    int d = (i < E) ? get_ei(ei, is64, (long)E + i) : (i - E);
    atomicAdd(&deg[d], 1);
}

__global__ __launch_bounds__(1024) void scan_kernel(const int* __restrict__ deg,
                                                    int* __restrict__ ptr,
                                                    int* __restrict__ cursor, int n) {
    __shared__ int sums[1024];
    int tid = threadIdx.x;
    int chunk = (n + 1023) >> 10;
    int beg = tid * chunk;
    int end = beg + chunk; if (end > n) end = n; if (beg > n) beg = n;
    int s = 0;
    for (int i = beg; i < end; ++i) s += deg[i];
    sums[tid] = s;
    __syncthreads();
    for (int off = 1; off < 1024; off <<= 1) {
        int v = (tid >= off) ? sums[tid - off] : 0;
        __syncthreads();
        sums[tid] += v;
        __syncthreads();
    }
    int base = (tid == 0) ? 0 : sums[tid - 1];
    for (int i = beg; i < end; ++i) {
        int d = deg[i];
        ptr[i] = base;
        cursor[i] = base;
        base += d;
    }
    if (tid == 1023) ptr[n] = sums[1023];
}

__global__ __launch_bounds__(256) void scatter_kernel(const int* __restrict__ ei,
                                                      const int* __restrict__ flag,
                                                      int* __restrict__ cursor,
                                                      int* __restrict__ csr_src, int E, int n) {
    int i = blockIdx.x * blockDim.x + threadIdx.x;
    int total = E + n;
    if (i >= total) return;
    int is64 = *flag;
    int s, d;
    if (i < E) {
        s = get_ei(ei, is64, i);
        d = get_ei(ei, is64, (long)E + i);
    } else {
        s = d = i - E;
    }
    int p = atomicAdd(&cursor[d], 1);
    csr_src[p] = s;
}

// ---------------------------------------------------------------------------
// Projection: h = x @ W  [N,K] x [K,64] -> [N,64], fused a_src/a_dst dots.
// One wave per node per iteration; lane = output feature. W column in VGPRs.
// ---------------------------------------------------------------------------
template <int K>
__global__ __launch_bounds__(256) void proj_kernel(const float* __restrict__ x,
                                                   const float* __restrict__ W,
                                                   const float* __restrict__ att_s,
                                                   const float* __restrict__ att_d,
                                                   float* __restrict__ h,
                                                   float* __restrict__ asrc,
                                                   float* __restrict__ adst, int n) {
    int lane = threadIdx.x & 63;
    int gwave = (blockIdx.x * blockDim.x + threadIdx.x) >> 6;
    int nwaves = (gridDim.x * blockDim.x) >> 6;

    float wcol[K];
#pragma unroll
    for (int k = 0; k < K; ++k) wcol[k] = W[k * 64 + lane];
    float as_f = att_s[lane], ad_f = att_d[lane];

    for (int node = gwave; node < n; node += nwaves) {
        const float4* xr = (const float4*)(x + (size_t)node * K);
        float a0 = 0.f, a1 = 0.f, a2 = 0.f, a3 = 0.f;
#pragma unroll
        for (int k4 = 0; k4 < K / 4; ++k4) {
            float4 xv = xr[k4];
            a0 = fmaf(xv.x, wcol[4 * k4 + 0], a0);
            a1 = fmaf(xv.y, wcol[4 * k4 + 1], a1);
            a2 = fmaf(xv.z, wcol[4 * k4 + 2], a2);
            a3 = fmaf(xv.w, wcol[4 * k4 + 3], a3);
        }
        float acc = (a0 + a1) + (a2 + a3);
        h[(size_t)node * 64 + lane] = acc;
        float ps = acc * as_f, pd = acc * ad_f;
#pragma unroll
        for (int off = 32; off; off >>= 1) {
            ps += __shfl_down(ps, off);
            pd += __shfl_down(pd, off);
        }
        if (lane == 0) {
            asrc[node] = ps;
            adst[node] = pd;
        }
    }
}

// ---------------------------------------------------------------------------
// Fused edge softmax + aggregation. One wave per dst node, lane = feature.
// Softmax computed WITHOUT max-subtraction (shift-invariant; e bounded ~ +-12
// for this data scale, so exp() is safe in fp32).
//   out[d][f] = (sum_e w_e * h[src_e][f]) / (sum_e w_e + 1e-16) + b[f]
// ---------------------------------------------------------------------------
__global__ __launch_bounds__(256) void agg_kernel(const int* __restrict__ ptr,
                                                  const int* __restrict__ srcs,
                                                  const float* __restrict__ h,
                                                  const float* __restrict__ asrc,
                                                  const float* __restrict__ adst,
                                                  const float* __restrict__ bias,
                                                  float* __restrict__ out, int n, int do_relu) {
    int lane = threadIdx.x & 63;
    int node = (blockIdx.x * blockDim.x + threadIdx.x) >> 6;
    if (node >= n) return;
    int beg = ptr[node], end = ptr[node + 1];
    float ad = adst[node];
    float acc = 0.f, wsum = 0.f;
    for (int j = beg; j < end; ++j) {
        int s = srcs[j];                      // broadcast load (uniform addr)
        float e = asrc[s] + ad;               // broadcast load
        e = (e > 0.f) ? e : NEG_SLOPE * e;
        float w = __expf(e);
        wsum += w;
        acc = fmaf(w, h[(size_t)s * 64 + lane], acc);  // coalesced 256B row
    }
    float o = acc / (wsum + 1e-16f) + bias[lane];
    if (do_relu) o = fmaxf(o, 0.f);
    out[(size_t)node * 64 + lane] = o;
}

// ---------------------------------------------------------------------------
// Global mean pool: out[f] = mean_n h[n][f]
// ---------------------------------------------------------------------------
__global__ __launch_bounds__(256) void mean_kernel(const float* __restrict__ h,
                                                   float* __restrict__ out, int n) {
    __shared__ float red[256];
    int f = threadIdx.x & 63;
    int w = threadIdx.x >> 6;
    int idx = blockIdx.x * 4 + w;
    int stride = gridDim.x * 4;
    float s = 0.f;
    for (int node = idx; node < n; node += stride) s += h[(size_t)node * 64 + f];
    red[threadIdx.x] = s;
    __syncthreads();
    if (w == 0) {
        float t = red[f] + red[64 + f] + red[128 + f] + red[192 + f];
        atomicAdd(&out[f], t / (float)n);
    }
}

extern "C" void kernel_launch(void* const* d_in, const int* in_sizes, int n_in,
                              void* d_out, int out_size, void* d_ws, size_t ws_size,
                              hipStream_t stream) {
    const float* x   = (const float*)d_in[0];
    const int*   ei  = (const int*)d_in[1];
    // d_in[2] = edge_attr (unused by reference, edge_dim=None)
    const float* W1  = (const float*)d_in[3];
    const float* as1 = (const float*)d_in[4];
    const float* ad1 = (const float*)d_in[5];
    const float* b1  = (const float*)d_in[6];
    const float* W2  = (const float*)d_in[7];
    const float* as2 = (const float*)d_in[8];
    const float* ad2 = (const float*)d_in[9];
    const float* b2  = (const float*)d_in[10];
    float* out = (float*)d_out;

    const int N = in_sizes[0] / 128;  // 100000
    const int E = in_sizes[1] / 2;    // 1600000
    const int T = E + N;              // edges incl. self-loops

    // Workspace carve-up (256B-aligned)
    size_t off = 0;
    char* base = (char*)d_ws;
    auto alloc = [&](size_t bytes) -> void* {
        void* p = base + off;
        off += (bytes + 255) & ~(size_t)255;
        return p;
    };
    int*   flag    = (int*)alloc(4);
    int*   deg     = (int*)alloc((size_t)N * 4);
    int*   ptr     = (int*)alloc(((size_t)N + 1) * 4);
    int*   cursor  = (int*)alloc((size_t)N * 4);
    int*   csr_src = (int*)alloc((size_t)T * 4);
    float* asrc    = (float*)alloc((size_t)N * 4);
    float* adst    = (float*)alloc((size_t)N * 4);
    float* bufA    = (float*)alloc((size_t)N * 64 * 4);
    float* bufB    = (float*)alloc((size_t)N * 64 * 4);
    (void)ws_size;

    // --- CSR build (shared by both layers) ---
    detect_kernel<<<1, 256, 0, stream>>>(ei, flag);
    hipMemsetAsync(deg, 0, (size_t)N * 4, stream);
    count_kernel<<<(T + 255) / 256, 256, 0, stream>>>(ei, flag, deg, E, N);
    scan_kernel<<<1, 1024, 0, stream>>>(deg, ptr, cursor, N);
    scatter_kernel<<<(T + 255) / 256, 256, 0, stream>>>(ei, flag, cursor, csr_src, E, N);

    // --- Layer 1: proj (x @ W1) + attention aggregate + ReLU ---
    proj_kernel<128><<<2048, 256, 0, stream>>>(x, W1, as1, ad1, bufA, asrc, adst, N);
    agg_kernel<<<(N * 64 + 255) / 256, 256, 0, stream>>>(ptr, csr_src, bufA, asrc, adst,
                                                         b1, bufB, N, 1);

    // --- Layer 2: proj (h @ W2) + attention aggregate ---
    proj_kernel<64><<<2048, 256, 0, stream>>>(bufB, W2, as2, ad2, bufA, asrc, adst, N);
    agg_kernel<<<(N * 64 + 255) / 256, 256, 0, stream>>>(ptr, csr_src, bufA, asrc, adst,
                                                         b2, bufB, N, 0);

    // --- Global mean pool ---
    hipMemsetAsync(out, 0, 64 * 4, stream);
    mean_kernel<<<256, 256, 0, stream>>>(bufB, out, N);
}

// Round 2
// 865.367 us; speedup vs baseline: 1.2530x; 1.2530x over previous
//
#include <hip/hip_runtime.h>
#include <hip/hip_bf16.h>
#include <cstdint>

#define NEG_SLOPE 0.2f
#define SCAN_ELEMS 1024   // elements per scan block (256 thr x 4)

// ---------------------------------------------------------------------------
// int64-vs-int32 edge_index detection.
// If edge_index is int64 (little-endian, values in [0,100000)), every odd
// int32 word of the src row is the zero high-word. If int32, odd words are
// random node ids (P(all zero) ~ 0). Flag: 1 => int64, 0 => int32.
// ---------------------------------------------------------------------------
__global__ __launch_bounds__(256) void detect_kernel(const int* __restrict__ ei,
                                                     int* __restrict__ flag) {
    __shared__ int red[256];
    int t = threadIdx.x;
    int v = 0;
    for (int i = t; i < 2048; i += 256) v |= ei[2 * i + 1];
    red[t] = v;
    __syncthreads();
    for (int off = 128; off; off >>= 1) {
        if (t < off) red[t] |= red[t + off];
        __syncthreads();
    }
    if (t == 0) *flag = (red[0] == 0) ? 1 : 0;
}

__device__ inline int get_ei(const int* ei, int is64, long idx) {
    return is64 ? ei[2 * idx] : ei[(int)idx];
}

// ---------------------------------------------------------------------------
// CSR build: degree histogram -> exclusive scan (3-phase) -> scatter.
// Edge i < E comes from edge_index; i in [E, E+N) is the self-loop (i-E).
// ---------------------------------------------------------------------------
__global__ __launch_bounds__(256) void count_kernel(const int* __restrict__ ei,
                                                    const int* __restrict__ flag,
                                                    int* __restrict__ deg, int E, int n) {
    int i = blockIdx.x * blockDim.x + threadIdx.x;
    int total = E + n;
    if (i >= total) return;
    int is64 = *flag;
    int d = (i < E) ? get_ei(ei, is64, (long)E + i) : (i - E);
    atomicAdd(&deg[d], 1);
}

// Phase 1: per-block sums. Block b covers deg[b*1024 .. b*1024+1023].
__global__ __launch_bounds__(256) void scan1_kernel(const int* __restrict__ deg,
                                                    int* __restrict__ bsums, int n) {
    int t = threadIdx.x;
    int i0 = blockIdx.x * SCAN_ELEMS + 4 * t;
    int4 v = make_int4(0, 0, 0, 0);
    if (i0 + 3 < n) v = *(const int4*)(deg + i0);
    else {
        if (i0 + 0 < n) v.x = deg[i0 + 0];
        if (i0 + 1 < n) v.y = deg[i0 + 1];
        if (i0 + 2 < n) v.z = deg[i0 + 2];
        if (i0 + 3 < n) v.w = deg[i0 + 3];
    }
    int s = v.x + v.y + v.z + v.w;
#pragma unroll
    for (int off = 32; off; off >>= 1) s += __shfl_down(s, off);
    __shared__ int ws[4];
    if ((t & 63) == 0) ws[t >> 6] = s;
    __syncthreads();
    if (t == 0) bsums[blockIdx.x] = ws[0] + ws[1] + ws[2] + ws[3];
}

// Phase 2: exclusive scan of the (<=256) block sums, single block.
__global__ __launch_bounds__(256) void scan2_kernel(int* __restrict__ bsums, int nb) {
    __shared__ int sh[256];
    int t = threadIdx.x;
    int v = (t < nb) ? bsums[t] : 0;
    sh[t] = v;
    __syncthreads();
    for (int off = 1; off < 256; off <<= 1) {
        int u = (t >= off) ? sh[t - off] : 0;
        __syncthreads();
        sh[t] += u;
        __syncthreads();
    }
    if (t < nb) bsums[t] = sh[t] - v;   // inclusive -> exclusive
}

// Phase 3: intra-block scan + block offset; write ptr & cursor (+ ptr[n]).
__global__ __launch_bounds__(256) void scan3_kernel(const int* __restrict__ deg,
                                                    const int* __restrict__ bsums,
                                                    int* __restrict__ ptr,
                                                    int* __restrict__ cursor, int n, int nb) {
    int b = blockIdx.x;
    int t = threadIdx.x;
    int i0 = b * SCAN_ELEMS + 4 * t;
    int4 v = make_int4(0, 0, 0, 0);
    if (i0 + 3 < n) v = *(const int4*)(deg + i0);
    else {
        if (i0 + 0 < n) v.x = deg[i0 + 0];
        if (i0 + 1 < n) v.y = deg[i0 + 1];
        if (i0 + 2 < n) v.z = deg[i0 + 2];
        if (i0 + 3 < n) v.w = deg[i0 + 3];
    }
    int s0 = v.x, s1 = s0 + v.y, s2 = s1 + v.z, s3 = s2 + v.w;  // thread-local inclusive
    __shared__ int sh[256];
    sh[t] = s3;
    __syncthreads();
    for (int off = 1; off < 256; off <<= 1) {
        int u = (t >= off) ? sh[t - off] : 0;
        __syncthreads();
        sh[t] += u;
        __syncthreads();
    }
    int excl = sh[t] - s3;              // exclusive prefix of this thread's chunk
    int base = bsums[b] + excl;
    if (i0 + 0 < n) { ptr[i0 + 0] = base;      cursor[i0 + 0] = base; }
    if (i0 + 1 < n) { ptr[i0 + 1] = base + s0; cursor[i0 + 1] = base + s0; }
    if (i0 + 2 < n) { ptr[i0 + 2] = base + s1; cursor[i0 + 2] = base + s1; }
    if (i0 + 3 < n) { ptr[i0 + 3] = base + s2; cursor[i0 + 3] = base + s2; }
    if (b == nb - 1 && t == 255) ptr[n] = base + s3;  // grand total
}

__global__ __launch_bounds__(256) void scatter_kernel(const int* __restrict__ ei,
                                                      const int* __restrict__ flag,
                                                      int* __restrict__ cursor,
                                                      int* __restrict__ csr_src, int E, int n) {
    int i = blockIdx.x * blockDim.x + threadIdx.x;
    int total = E + n;
    if (i >= total) return;
    int is64 = *flag;
    int s, d;
    if (i < E) {
        s = get_ei(ei, is64, i);
        d = get_ei(ei, is64, (long)E + i);
    } else {
        s = d = i - E;
    }
    int p = atomicAdd(&cursor[d], 1);
    csr_src[p] = s;
}

// ---------------------------------------------------------------------------
// Projection: h = x @ W  [N,K] x [K,64] -> [N,64], fused a_src/a_dst dots.
// One wave per node per iteration; lane = output feature. W column in VGPRs.
// ---------------------------------------------------------------------------
template <int K>
__global__ __launch_bounds__(256) void proj_kernel(const float* __restrict__ x,
                                                   const float* __restrict__ W,
                                                   const float* __restrict__ att_s,
                                                   const float* __restrict__ att_d,
                                                   float* __restrict__ h,
                                                   float* __restrict__ asrc,
                                                   float* __restrict__ adst, int n) {
    int lane = threadIdx.x & 63;
    int gwave = (blockIdx.x * blockDim.x + threadIdx.x) >> 6;
    int nwaves = (gridDim.x * blockDim.x) >> 6;

    float wcol[K];
#pragma unroll
    for (int k = 0; k < K; ++k) wcol[k] = W[k * 64 + lane];
    float as_f = att_s[lane], ad_f = att_d[lane];

    for (int node = gwave; node < n; node += nwaves) {
        const float4* xr = (const float4*)(x + (size_t)node * K);
        float a0 = 0.f, a1 = 0.f, a2 = 0.f, a3 = 0.f;
#pragma unroll
        for (int k4 = 0; k4 < K / 4; ++k4) {
            float4 xv = xr[k4];
            a0 = fmaf(xv.x, wcol[4 * k4 + 0], a0);
            a1 = fmaf(xv.y, wcol[4 * k4 + 1], a1);
            a2 = fmaf(xv.z, wcol[4 * k4 + 2], a2);
            a3 = fmaf(xv.w, wcol[4 * k4 + 3], a3);
        }
        float acc = (a0 + a1) + (a2 + a3);
        h[(size_t)node * 64 + lane] = acc;
        float ps = acc * as_f, pd = acc * ad_f;
#pragma unroll
        for (int off = 32; off; off >>= 1) {
            ps += __shfl_down(ps, off);
            pd += __shfl_down(pd, off);
        }
        if (lane == 0) {
            asrc[node] = ps;
            adst[node] = pd;
        }
    }
}

// ---------------------------------------------------------------------------
// Fused edge softmax + aggregation. One wave per dst node, lane = feature.
// Softmax computed WITHOUT max-subtraction (shift-invariant; e bounded ~ +-12
// for this data scale, so exp() is safe in fp32).
//   out[d][f] = (sum_e w_e * h[src_e][f]) / (sum_e w_e + 1e-16) + b[f]
// ---------------------------------------------------------------------------
__global__ __launch_bounds__(256) void agg_kernel(const int* __restrict__ ptr,
                                                  const int* __restrict__ srcs,
                                                  const float* __restrict__ h,
                                                  const float* __restrict__ asrc,
                                                  const float* __restrict__ adst,
                                                  const float* __restrict__ bias,
                                                  float* __restrict__ out, int n, int do_relu) {
    int lane = threadIdx.x & 63;
    int node = (blockIdx.x * blockDim.x + threadIdx.x) >> 6;
    if (node >= n) return;
    int beg = ptr[node], end = ptr[node + 1];
    float ad = adst[node];
    float acc = 0.f, wsum = 0.f;
    for (int j = beg; j < end; ++j) {
        int s = srcs[j];                      // wave-uniform load
        float e = asrc[s] + ad;               // broadcast load
        e = (e > 0.f) ? e : NEG_SLOPE * e;
        float w = __expf(e);
        wsum += w;
        acc = fmaf(w, h[(size_t)s * 64 + lane], acc);  // coalesced 256B row
    }
    float o = acc / (wsum + 1e-16f) + bias[lane];
    if (do_relu) o = fmaxf(o, 0.f);
    out[(size_t)node * 64 + lane] = o;
}

// ---------------------------------------------------------------------------
// Global mean pool: out[f] = mean_n h[n][f]
// ---------------------------------------------------------------------------
__global__ __launch_bounds__(256) void mean_kernel(const float* __restrict__ h,
                                                   float* __restrict__ out, int n) {
    __shared__ float red[256];
    int f = threadIdx.x & 63;
    int w = threadIdx.x >> 6;
    int idx = blockIdx.x * 4 + w;
    int stride = gridDim.x * 4;
    float s = 0.f;
    for (int node = idx; node < n; node += stride) s += h[(size_t)node * 64 + f];
    red[threadIdx.x] = s;
    __syncthreads();
    if (w == 0) {
        float t = red[f] + red[64 + f] + red[128 + f] + red[192 + f];
        atomicAdd(&out[f], t / (float)n);
    }
}

extern "C" void kernel_launch(void* const* d_in, const int* in_sizes, int n_in,
                              void* d_out, int out_size, void* d_ws, size_t ws_size,
                              hipStream_t stream) {
    const float* x   = (const float*)d_in[0];
    const int*   ei  = (const int*)d_in[1];
    // d_in[2] = edge_attr (unused by reference, edge_dim=None)
    const float* W1  = (const float*)d_in[3];
    const float* as1 = (const float*)d_in[4];
    const float* ad1 = (const float*)d_in[5];
    const float* b1  = (const float*)d_in[6];
    const float* W2  = (const float*)d_in[7];
    const float* as2 = (const float*)d_in[8];
    const float* ad2 = (const float*)d_in[9];
    const float* b2  = (const float*)d_in[10];
    float* out = (float*)d_out;

    const int N = in_sizes[0] / 128;  // 100000
    const int E = in_sizes[1] / 2;    // 1600000
    const int T = E + N;              // edges incl. self-loops
    const int NB = (N + SCAN_ELEMS - 1) / SCAN_ELEMS;  // scan blocks (98) <= 256

    // Workspace carve-up (256B-aligned)
    size_t off = 0;
    char* base = (char*)d_ws;
    auto alloc = [&](size_t bytes) -> void* {
        void* p = base + off;
        off += (bytes + 255) & ~(size_t)255;
        return p;
    };
    int*   flag    = (int*)alloc(4);
    int*   deg     = (int*)alloc((size_t)N * 4);
    int*   ptr     = (int*)alloc(((size_t)N + 1) * 4);
    int*   cursor  = (int*)alloc((size_t)N * 4);
    int*   bsums   = (int*)alloc(256 * 4);
    int*   csr_src = (int*)alloc((size_t)T * 4);
    float* asrc    = (float*)alloc((size_t)N * 4);
    float* adst    = (float*)alloc((size_t)N * 4);
    float* bufA    = (float*)alloc((size_t)N * 64 * 4);
    float* bufB    = (float*)alloc((size_t)N * 64 * 4);
    (void)ws_size;

    // --- CSR build (shared by both layers) ---
    detect_kernel<<<1, 256, 0, stream>>>(ei, flag);
    hipMemsetAsync(deg, 0, (size_t)N * 4, stream);
    count_kernel<<<(T + 255) / 256, 256, 0, stream>>>(ei, flag, deg, E, N);
    scan1_kernel<<<NB, 256, 0, stream>>>(deg, bsums, N);
    scan2_kernel<<<1, 256, 0, stream>>>(bsums, NB);
    scan3_kernel<<<NB, 256, 0, stream>>>(deg, bsums, ptr, cursor, N, NB);
    scatter_kernel<<<(T + 255) / 256, 256, 0, stream>>>(ei, flag, cursor, csr_src, E, N);

    // --- Layer 1: proj (x @ W1) + attention aggregate + ReLU ---
    proj_kernel<128><<<2048, 256, 0, stream>>>(x, W1, as1, ad1, bufA, asrc, adst, N);
    agg_kernel<<<(N * 64 + 255) / 256, 256, 0, stream>>>(ptr, csr_src, bufA, asrc, adst,
                                                         b1, bufB, N, 1);

    // --- Layer 2: proj (h @ W2) + attention aggregate ---
    proj_kernel<64><<<2048, 256, 0, stream>>>(bufB, W2, as2, ad2, bufA, asrc, adst, N);
    agg_kernel<<<(N * 64 + 255) / 256, 256, 0, stream>>>(ptr, csr_src, bufA, asrc, adst,
                                                         b2, bufB, N, 0);

    // --- Global mean pool ---
    hipMemsetAsync(out, 0, 64 * 4, stream);
    mean_kernel<<<256, 256, 0, stream>>>(bufB, out, N);
}

// Round 3
// 682.435 us; speedup vs baseline: 1.5888x; 1.2681x over previous
//
#include <hip/hip_runtime.h>
#include <hip/hip_bf16.h>
#include <cstdint>

#define NEG_SLOPE 0.2f
#define SCAN_ELEMS 1024   // elements per scan block (256 thr x 4)

// ---------------------------------------------------------------------------
// int64-vs-int32 edge_index detection.
// If edge_index is int64 (little-endian, values in [0,100000)), every odd
// int32 word of the src row is the zero high-word. If int32, odd words are
// random node ids (P(all zero) ~ 0). Flag: 1 => int64, 0 => int32.
// ---------------------------------------------------------------------------
__global__ __launch_bounds__(256) void detect_kernel(const int* __restrict__ ei,
                                                     int* __restrict__ flag) {
    __shared__ int red[256];
    int t = threadIdx.x;
    int v = 0;
    for (int i = t; i < 2048; i += 256) v |= ei[2 * i + 1];
    red[t] = v;
    __syncthreads();
    for (int off = 128; off; off >>= 1) {
        if (t < off) red[t] |= red[t + off];
        __syncthreads();
    }
    if (t == 0) *flag = (red[0] == 0) ? 1 : 0;
}

__device__ inline int get_ei(const int* ei, int is64, long idx) {
    return is64 ? ei[2 * idx] : ei[(int)idx];
}

// ---------------------------------------------------------------------------
// CSR build: degree histogram -> exclusive scan (3-phase) -> scatter.
// Edge i < E comes from edge_index; i in [E, E+N) is the self-loop (i-E).
// ---------------------------------------------------------------------------
__global__ __launch_bounds__(256) void count_kernel(const int* __restrict__ ei,
                                                    const int* __restrict__ flag,
                                                    int* __restrict__ deg, int E, int n) {
    int i = blockIdx.x * blockDim.x + threadIdx.x;
    int total = E + n;
    if (i >= total) return;
    int is64 = *flag;
    int d = (i < E) ? get_ei(ei, is64, (long)E + i) : (i - E);
    atomicAdd(&deg[d], 1);
}

// Phase 1: per-block sums. Block b covers deg[b*1024 .. b*1024+1023].
__global__ __launch_bounds__(256) void scan1_kernel(const int* __restrict__ deg,
                                                    int* __restrict__ bsums, int n) {
    int t = threadIdx.x;
    int i0 = blockIdx.x * SCAN_ELEMS + 4 * t;
    int4 v = make_int4(0, 0, 0, 0);
    if (i0 + 3 < n) v = *(const int4*)(deg + i0);
    else {
        if (i0 + 0 < n) v.x = deg[i0 + 0];
        if (i0 + 1 < n) v.y = deg[i0 + 1];
        if (i0 + 2 < n) v.z = deg[i0 + 2];
        if (i0 + 3 < n) v.w = deg[i0 + 3];
    }
    int s = v.x + v.y + v.z + v.w;
#pragma unroll
    for (int off = 32; off; off >>= 1) s += __shfl_down(s, off);
    __shared__ int ws[4];
    if ((t & 63) == 0) ws[t >> 6] = s;
    __syncthreads();
    if (t == 0) bsums[blockIdx.x] = ws[0] + ws[1] + ws[2] + ws[3];
}

// Phase 2: exclusive scan of the (<=256) block sums, single block.
__global__ __launch_bounds__(256) void scan2_kernel(int* __restrict__ bsums, int nb) {
    __shared__ int sh[256];
    int t = threadIdx.x;
    int v = (t < nb) ? bsums[t] : 0;
    sh[t] = v;
    __syncthreads();
    for (int off = 1; off < 256; off <<= 1) {
        int u = (t >= off) ? sh[t - off] : 0;
        __syncthreads();
        sh[t] += u;
        __syncthreads();
    }
    if (t < nb) bsums[t] = sh[t] - v;   // inclusive -> exclusive
}

// Phase 3: intra-block scan + block offset; write ptr & cursor (+ ptr[n]).
__global__ __launch_bounds__(256) void scan3_kernel(const int* __restrict__ deg,
                                                    const int* __restrict__ bsums,
                                                    int* __restrict__ ptr,
                                                    int* __restrict__ cursor, int n, int nb) {
    int b = blockIdx.x;
    int t = threadIdx.x;
    int i0 = b * SCAN_ELEMS + 4 * t;
    int4 v = make_int4(0, 0, 0, 0);
    if (i0 + 3 < n) v = *(const int4*)(deg + i0);
    else {
        if (i0 + 0 < n) v.x = deg[i0 + 0];
        if (i0 + 1 < n) v.y = deg[i0 + 1];
        if (i0 + 2 < n) v.z = deg[i0 + 2];
        if (i0 + 3 < n) v.w = deg[i0 + 3];
    }
    int s0 = v.x, s1 = s0 + v.y, s2 = s1 + v.z, s3 = s2 + v.w;  // thread-local inclusive
    __shared__ int sh[256];
    sh[t] = s3;
    __syncthreads();
    for (int off = 1; off < 256; off <<= 1) {
        int u = (t >= off) ? sh[t - off] : 0;
        __syncthreads();
        sh[t] += u;
        __syncthreads();
    }
    int excl = sh[t] - s3;              // exclusive prefix of this thread's chunk
    int base = bsums[b] + excl;
    if (i0 + 0 < n) { ptr[i0 + 0] = base;      cursor[i0 + 0] = base; }
    if (i0 + 1 < n) { ptr[i0 + 1] = base + s0; cursor[i0 + 1] = base + s0; }
    if (i0 + 2 < n) { ptr[i0 + 2] = base + s1; cursor[i0 + 2] = base + s1; }
    if (i0 + 3 < n) { ptr[i0 + 3] = base + s2; cursor[i0 + 3] = base + s2; }
    if (b == nb - 1 && t == 255) ptr[n] = base + s3;  // grand total
}

__global__ __launch_bounds__(256) void scatter_kernel(const int* __restrict__ ei,
                                                      const int* __restrict__ flag,
                                                      int* __restrict__ cursor,
                                                      int* __restrict__ csr_src, int E, int n) {
    int i = blockIdx.x * blockDim.x + threadIdx.x;
    int total = E + n;
    if (i >= total) return;
    int is64 = *flag;
    int s, d;
    if (i < E) {
        s = get_ei(ei, is64, i);
        d = get_ei(ei, is64, (long)E + i);
    } else {
        s = d = i - E;
    }
    int p = atomicAdd(&cursor[d], 1);
    csr_src[p] = s;
}

// ---------------------------------------------------------------------------
// Projection: h = x @ W  [N,K] x [K,64] -> [N,64], fused a_src/a_dst dots.
// One wave per node per iteration; lane = output feature. W column in VGPRs.
// ---------------------------------------------------------------------------
template <int K>
__global__ __launch_bounds__(256) void proj_kernel(const float* __restrict__ x,
                                                   const float* __restrict__ W,
                                                   const float* __restrict__ att_s,
                                                   const float* __restrict__ att_d,
                                                   float* __restrict__ h,
                                                   float* __restrict__ asrc,
                                                   float* __restrict__ adst, int n) {
    int lane = threadIdx.x & 63;
    int gwave = (blockIdx.x * blockDim.x + threadIdx.x) >> 6;
    int nwaves = (gridDim.x * blockDim.x) >> 6;

    float wcol[K];
#pragma unroll
    for (int k = 0; k < K; ++k) wcol[k] = W[k * 64 + lane];
    float as_f = att_s[lane], ad_f = att_d[lane];

    for (int node = gwave; node < n; node += nwaves) {
        const float4* xr = (const float4*)(x + (size_t)node * K);
        float a0 = 0.f, a1 = 0.f, a2 = 0.f, a3 = 0.f;
#pragma unroll
        for (int k4 = 0; k4 < K / 4; ++k4) {
            float4 xv = xr[k4];
            a0 = fmaf(xv.x, wcol[4 * k4 + 0], a0);
            a1 = fmaf(xv.y, wcol[4 * k4 + 1], a1);
            a2 = fmaf(xv.z, wcol[4 * k4 + 2], a2);
            a3 = fmaf(xv.w, wcol[4 * k4 + 3], a3);
        }
        float acc = (a0 + a1) + (a2 + a3);
        h[(size_t)node * 64 + lane] = acc;
        float ps = acc * as_f, pd = acc * ad_f;
#pragma unroll
        for (int off = 32; off; off >>= 1) {
            ps += __shfl_down(ps, off);
            pd += __shfl_down(pd, off);
        }
        if (lane == 0) {
            asrc[node] = ps;
            adst[node] = pd;
        }
    }
}

// ---------------------------------------------------------------------------
// Fused edge softmax + aggregation. One wave per dst node, lane = feature.
// Softmax WITHOUT max-subtraction (shift-invariant; |e| bounded ~12 here).
// Edge loop unrolled x8: batches the srcs/asrc/h gathers so ~8 independent
// memory ops are in flight per wave instead of 1 dependent chain per edge.
// ---------------------------------------------------------------------------
__global__ __launch_bounds__(256) void agg_kernel(const int* __restrict__ ptr,
                                                  const int* __restrict__ srcs,
                                                  const float* __restrict__ h,
                                                  const float* __restrict__ asrc,
                                                  const float* __restrict__ adst,
                                                  const float* __restrict__ bias,
                                                  float* __restrict__ out, int n, int do_relu) {
    int lane = threadIdx.x & 63;
    int node = (blockIdx.x * blockDim.x + threadIdx.x) >> 6;
    if (node >= n) return;
    int beg = ptr[node], end = ptr[node + 1];
    float ad = adst[node];
    float acc = 0.f, wsum = 0.f;
    int j = beg;
    for (; j + 8 <= end; j += 8) {
        int s[8];
#pragma unroll
        for (int u = 0; u < 8; ++u) s[u] = srcs[j + u];
        float ea[8];
#pragma unroll
        for (int u = 0; u < 8; ++u) ea[u] = asrc[s[u]];
        float hv[8];
#pragma unroll
        for (int u = 0; u < 8; ++u) hv[u] = h[(size_t)s[u] * 64 + lane];
#pragma unroll
        for (int u = 0; u < 8; ++u) {
            float e = ea[u] + ad;
            e = (e > 0.f) ? e : NEG_SLOPE * e;
            float w = __expf(e);
            wsum += w;
            acc = fmaf(w, hv[u], acc);
        }
    }
    for (; j < end; ++j) {
        int s = srcs[j];
        float e = asrc[s] + ad;
        e = (e > 0.f) ? e : NEG_SLOPE * e;
        float w = __expf(e);
        wsum += w;
        acc = fmaf(w, h[(size_t)s * 64 + lane], acc);
    }
    float o = acc / (wsum + 1e-16f) + bias[lane];
    if (do_relu) o = fmaxf(o, 0.f);
    out[(size_t)node * 64 + lane] = o;
}

// ---------------------------------------------------------------------------
// Global mean pool: out[f] = mean_n h[n][f]
// ---------------------------------------------------------------------------
__global__ __launch_bounds__(256) void mean_kernel(const float* __restrict__ h,
                                                   float* __restrict__ out, int n) {
    __shared__ float red[256];
    int f = threadIdx.x & 63;
    int w = threadIdx.x >> 6;
    int idx = blockIdx.x * 4 + w;
    int stride = gridDim.x * 4;
    float s = 0.f;
    for (int node = idx; node < n; node += stride) s += h[(size_t)node * 64 + f];
    red[threadIdx.x] = s;
    __syncthreads();
    if (w == 0) {
        float t = red[f] + red[64 + f] + red[128 + f] + red[192 + f];
        atomicAdd(&out[f], t / (float)n);
    }
}

extern "C" void kernel_launch(void* const* d_in, const int* in_sizes, int n_in,
                              void* d_out, int out_size, void* d_ws, size_t ws_size,
                              hipStream_t stream) {
    const float* x   = (const float*)d_in[0];
    const int*   ei  = (const int*)d_in[1];
    // d_in[2] = edge_attr (unused by reference, edge_dim=None)
    const float* W1  = (const float*)d_in[3];
    const float* as1 = (const float*)d_in[4];
    const float* ad1 = (const float*)d_in[5];
    const float* b1  = (const float*)d_in[6];
    const float* W2  = (const float*)d_in[7];
    const float* as2 = (const float*)d_in[8];
    const float* ad2 = (const float*)d_in[9];
    const float* b2  = (const float*)d_in[10];
    float* out = (float*)d_out;

    const int N = in_sizes[0] / 128;  // 100000
    const int E = in_sizes[1] / 2;    // 1600000
    const int T = E + N;              // edges incl. self-loops
    const int NB = (N + SCAN_ELEMS - 1) / SCAN_ELEMS;  // scan blocks (98) <= 256

    // Workspace carve-up (256B-aligned)
    size_t off = 0;
    char* base = (char*)d_ws;
    auto alloc = [&](size_t bytes) -> void* {
        void* p = base + off;
        off += (bytes + 255) & ~(size_t)255;
        return p;
    };
    int*   flag    = (int*)alloc(4);
    int*   deg     = (int*)alloc((size_t)N * 4);
    int*   ptr     = (int*)alloc(((size_t)N + 1) * 4);
    int*   cursor  = (int*)alloc((size_t)N * 4);
    int*   bsums   = (int*)alloc(256 * 4);
    int*   csr_src = (int*)alloc((size_t)T * 4);
    float* asrc    = (float*)alloc((size_t)N * 4);
    float* adst    = (float*)alloc((size_t)N * 4);
    float* bufA    = (float*)alloc((size_t)N * 64 * 4);
    float* bufB    = (float*)alloc((size_t)N * 64 * 4);
    (void)ws_size;

    // --- CSR build (shared by both layers) ---
    detect_kernel<<<1, 256, 0, stream>>>(ei, flag);
    hipMemsetAsync(deg, 0, (size_t)N * 4, stream);
    count_kernel<<<(T + 255) / 256, 256, 0, stream>>>(ei, flag, deg, E, N);
    scan1_kernel<<<NB, 256, 0, stream>>>(deg, bsums, N);
    scan2_kernel<<<1, 256, 0, stream>>>(bsums, NB);
    scan3_kernel<<<NB, 256, 0, stream>>>(deg, bsums, ptr, cursor, N, NB);
    scatter_kernel<<<(T + 255) / 256, 256, 0, stream>>>(ei, flag, cursor, csr_src, E, N);

    // --- Layer 1: proj (x @ W1) + attention aggregate + ReLU ---
    proj_kernel<128><<<2048, 256, 0, stream>>>(x, W1, as1, ad1, bufA, asrc, adst, N);
    agg_kernel<<<(N * 64 + 255) / 256, 256, 0, stream>>>(ptr, csr_src, bufA, asrc, adst,
                                                         b1, bufB, N, 1);

    // --- Layer 2: proj (h @ W2) + attention aggregate ---
    proj_kernel<64><<<2048, 256, 0, stream>>>(bufB, W2, as2, ad2, bufA, asrc, adst, N);
    agg_kernel<<<(N * 64 + 255) / 256, 256, 0, stream>>>(ptr, csr_src, bufA, asrc, adst,
                                                         b2, bufB, N, 0);

    // --- Global mean pool ---
    hipMemsetAsync(out, 0, 64 * 4, stream);
    mean_kernel<<<256, 256, 0, stream>>>(bufB, out, N);
}

// Round 4
// 556.954 us; speedup vs baseline: 1.9468x; 1.2253x over previous
//
#include <hip/hip_runtime.h>
#include <hip/hip_bf16.h>
#include <cstdint>

#define NEG_SLOPE 0.2f
#define SCAN_ELEMS 1024   // elements per scan block (256 thr x 4)

// ---------------------------------------------------------------------------
// int64-vs-int32 edge_index detection.
// ---------------------------------------------------------------------------
__global__ __launch_bounds__(256) void detect_kernel(const int* __restrict__ ei,
                                                     int* __restrict__ flag) {
    __shared__ int red[256];
    int t = threadIdx.x;
    int v = 0;
    for (int i = t; i < 2048; i += 256) v |= ei[2 * i + 1];
    red[t] = v;
    __syncthreads();
    for (int off = 128; off; off >>= 1) {
        if (t < off) red[t] |= red[t + off];
        __syncthreads();
    }
    if (t == 0) *flag = (red[0] == 0) ? 1 : 0;
}

__device__ inline int get_ei(const int* ei, int is64, long idx) {
    return is64 ? ei[2 * idx] : ei[(int)idx];
}

// ---------------------------------------------------------------------------
// CSR build: degree histogram -> exclusive scan (3-phase) -> scatter.
// ---------------------------------------------------------------------------
__global__ __launch_bounds__(256) void count_kernel(const int* __restrict__ ei,
                                                    const int* __restrict__ flag,
                                                    int* __restrict__ deg, int E, int n) {
    int i = blockIdx.x * blockDim.x + threadIdx.x;
    int total = E + n;
    if (i >= total) return;
    int is64 = *flag;
    int d = (i < E) ? get_ei(ei, is64, (long)E + i) : (i - E);
    atomicAdd(&deg[d], 1);
}

// Phase 1: per-block sums.
__global__ __launch_bounds__(256) void scan1_kernel(const int* __restrict__ deg,
                                                    int* __restrict__ bsums, int n) {
    int t = threadIdx.x;
    int i0 = blockIdx.x * SCAN_ELEMS + 4 * t;
    int4 v = make_int4(0, 0, 0, 0);
    if (i0 + 3 < n) v = *(const int4*)(deg + i0);
    else {
        if (i0 + 0 < n) v.x = deg[i0 + 0];
        if (i0 + 1 < n) v.y = deg[i0 + 1];
        if (i0 + 2 < n) v.z = deg[i0 + 2];
        if (i0 + 3 < n) v.w = deg[i0 + 3];
    }
    int s = v.x + v.y + v.z + v.w;
#pragma unroll
    for (int off = 32; off; off >>= 1) s += __shfl_down(s, off);
    __shared__ int ws[4];
    if ((t & 63) == 0) ws[t >> 6] = s;
    __syncthreads();
    if (t == 0) bsums[blockIdx.x] = ws[0] + ws[1] + ws[2] + ws[3];
}

// Phase 2: exclusive scan of the (<=256) block sums, single block.
__global__ __launch_bounds__(256) void scan2_kernel(int* __restrict__ bsums, int nb) {
    __shared__ int sh[256];
    int t = threadIdx.x;
    int v = (t < nb) ? bsums[t] : 0;
    sh[t] = v;
    __syncthreads();
    for (int off = 1; off < 256; off <<= 1) {
        int u = (t >= off) ? sh[t - off] : 0;
        __syncthreads();
        sh[t] += u;
        __syncthreads();
    }
    if (t < nb) bsums[t] = sh[t] - v;   // inclusive -> exclusive
}

// Phase 3: intra-block scan + block offset; write ptr & cursor (+ ptr[n]).
__global__ __launch_bounds__(256) void scan3_kernel(const int* __restrict__ deg,
                                                    const int* __restrict__ bsums,
                                                    int* __restrict__ ptr,
                                                    int* __restrict__ cursor, int n, int nb) {
    int b = blockIdx.x;
    int t = threadIdx.x;
    int i0 = b * SCAN_ELEMS + 4 * t;
    int4 v = make_int4(0, 0, 0, 0);
    if (i0 + 3 < n) v = *(const int4*)(deg + i0);
    else {
        if (i0 + 0 < n) v.x = deg[i0 + 0];
        if (i0 + 1 < n) v.y = deg[i0 + 1];
        if (i0 + 2 < n) v.z = deg[i0 + 2];
        if (i0 + 3 < n) v.w = deg[i0 + 3];
    }
    int s0 = v.x, s1 = s0 + v.y, s2 = s1 + v.z, s3 = s2 + v.w;
    __shared__ int sh[256];
    sh[t] = s3;
    __syncthreads();
    for (int off = 1; off < 256; off <<= 1) {
        int u = (t >= off) ? sh[t - off] : 0;
        __syncthreads();
        sh[t] += u;
        __syncthreads();
    }
    int excl = sh[t] - s3;
    int base = bsums[b] + excl;
    if (i0 + 0 < n) { ptr[i0 + 0] = base;      cursor[i0 + 0] = base; }
    if (i0 + 1 < n) { ptr[i0 + 1] = base + s0; cursor[i0 + 1] = base + s0; }
    if (i0 + 2 < n) { ptr[i0 + 2] = base + s1; cursor[i0 + 2] = base + s1; }
    if (i0 + 3 < n) { ptr[i0 + 3] = base + s2; cursor[i0 + 3] = base + s2; }
    if (b == nb - 1 && t == 255) ptr[n] = base + s3;
}

__global__ __launch_bounds__(256) void scatter_kernel(const int* __restrict__ ei,
                                                      const int* __restrict__ flag,
                                                      int* __restrict__ cursor,
                                                      int* __restrict__ csr_src, int E, int n) {
    int i = blockIdx.x * blockDim.x + threadIdx.x;
    int total = E + n;
    if (i >= total) return;
    int is64 = *flag;
    int s, d;
    if (i < E) {
        s = get_ei(ei, is64, i);
        d = get_ei(ei, is64, (long)E + i);
    } else {
        s = d = i - E;
    }
    int p = atomicAdd(&cursor[d], 1);
    csr_src[p] = s;
}

// ---------------------------------------------------------------------------
// Projection as register-tiled GEMM: h = x @ W  [N,K] x [K,64] -> [N,64],
// fused a_src/a_dst dots.
// Block = 64 nodes x 64 feats. Thread (tn=tid>>4, tf=tid&15) owns a 4x4 tile.
// x-tile staged in LDS (row pad +4 floats keeps float4 alignment and makes
// the 4-distinct-address x reads 2-way-bank at worst = free). W read from
// global inside the k-loop: 32/16 KB, L1-resident, 256 B distinct per load.
// ---------------------------------------------------------------------------
template <int K>
__global__ __launch_bounds__(256) void proj_gemm(const float* __restrict__ x,
                                                 const float* __restrict__ W,
                                                 const float* __restrict__ att_s,
                                                 const float* __restrict__ att_d,
                                                 float* __restrict__ h,
                                                 float* __restrict__ asrc,
                                                 float* __restrict__ adst, int n) {
    constexpr int KP = K + 4;            // padded row stride (floats)
    constexpr int ROWF4 = K / 4;         // float4 per x row
    __shared__ float xs[64 * KP];
    int tid = threadIdx.x;
    int node0 = blockIdx.x * 64;

    // Stage x-tile: coalesced float4 loads, rows beyond n -> zeros.
#pragma unroll
    for (int r = 0; r < (64 * ROWF4) / 256; ++r) {
        int f4 = tid + 256 * r;
        int row = f4 / ROWF4, c4 = f4 % ROWF4;
        float4 v = make_float4(0.f, 0.f, 0.f, 0.f);
        if (node0 + row < n) v = *(const float4*)(x + (size_t)(node0 + row) * K + 4 * c4);
        *(float4*)(xs + row * KP + 4 * c4) = v;
    }
    __syncthreads();

    int tf = tid & 15, tn = tid >> 4;
    float acc[4][4];
#pragma unroll
    for (int i = 0; i < 4; ++i)
#pragma unroll
        for (int j = 0; j < 4; ++j) acc[i][j] = 0.f;

    const float* wp = W + 4 * tf;
    const float* xp = xs + 4 * tn * KP;
#pragma unroll 4
    for (int k4 = 0; k4 < K / 4; ++k4) {
        float4 wv[4];
#pragma unroll
        for (int kk = 0; kk < 4; ++kk)
            wv[kk] = *(const float4*)(wp + (size_t)(4 * k4 + kk) * 64);
        float4 xv[4];
#pragma unroll
        for (int i = 0; i < 4; ++i)
            xv[i] = *(const float4*)(xp + i * KP + 4 * k4);
#pragma unroll
        for (int i = 0; i < 4; ++i) {
            const float xk[4] = {xv[i].x, xv[i].y, xv[i].z, xv[i].w};
#pragma unroll
            for (int kk = 0; kk < 4; ++kk) {
                const float* wf = (const float*)&wv[kk];
#pragma unroll
                for (int j = 0; j < 4; ++j) acc[i][j] = fmaf(xk[kk], wf[j], acc[i][j]);
            }
        }
    }

    // Epilogue: store h tile + fused attention dots with 16-lane shfl reduce.
    float4 as = *(const float4*)(att_s + 4 * tf);
    float4 ad = *(const float4*)(att_d + 4 * tf);
#pragma unroll
    for (int i = 0; i < 4; ++i) {
        int node = node0 + 4 * tn + i;
        float ps = acc[i][0] * as.x + acc[i][1] * as.y + acc[i][2] * as.z + acc[i][3] * as.w;
        float pd = acc[i][0] * ad.x + acc[i][1] * ad.y + acc[i][2] * ad.z + acc[i][3] * ad.w;
#pragma unroll
        for (int off = 1; off < 16; off <<= 1) {
            ps += __shfl_xor(ps, off);
            pd += __shfl_xor(pd, off);
        }
        if (node < n) {
            *(float4*)(h + (size_t)node * 64 + 4 * tf) =
                make_float4(acc[i][0], acc[i][1], acc[i][2], acc[i][3]);
            if (tf == 0) { asrc[node] = ps; adst[node] = pd; }
        }
    }
}

// ---------------------------------------------------------------------------
// Fused edge softmax + aggregation. One wave per dst node, lane = feature.
// Softmax WITHOUT max-subtraction (shift-invariant; |e| bounded ~12 here).
// Edge loop unrolled x8 for memory-level parallelism.
// ---------------------------------------------------------------------------
__global__ __launch_bounds__(256) void agg_kernel(const int* __restrict__ ptr,
                                                  const int* __restrict__ srcs,
                                                  const float* __restrict__ h,
                                                  const float* __restrict__ asrc,
                                                  const float* __restrict__ adst,
                                                  const float* __restrict__ bias,
                                                  float* __restrict__ out, int n, int do_relu) {
    int lane = threadIdx.x & 63;
    int node = (blockIdx.x * blockDim.x + threadIdx.x) >> 6;
    if (node >= n) return;
    int beg = ptr[node], end = ptr[node + 1];
    float ad = adst[node];
    float acc = 0.f, wsum = 0.f;
    int j = beg;
    for (; j + 8 <= end; j += 8) {
        int s[8];
#pragma unroll
        for (int u = 0; u < 8; ++u) s[u] = srcs[j + u];
        float ea[8];
#pragma unroll
        for (int u = 0; u < 8; ++u) ea[u] = asrc[s[u]];
        float hv[8];
#pragma unroll
        for (int u = 0; u < 8; ++u) hv[u] = h[(size_t)s[u] * 64 + lane];
#pragma unroll
        for (int u = 0; u < 8; ++u) {
            float e = ea[u] + ad;
            e = (e > 0.f) ? e : NEG_SLOPE * e;
            float w = __expf(e);
            wsum += w;
            acc = fmaf(w, hv[u], acc);
        }
    }
    for (; j < end; ++j) {
        int s = srcs[j];
        float e = asrc[s] + ad;
        e = (e > 0.f) ? e : NEG_SLOPE * e;
        float w = __expf(e);
        wsum += w;
        acc = fmaf(w, h[(size_t)s * 64 + lane], acc);
    }
    float o = acc / (wsum + 1e-16f) + bias[lane];
    if (do_relu) o = fmaxf(o, 0.f);
    out[(size_t)node * 64 + lane] = o;
}

// ---------------------------------------------------------------------------
// Global mean pool: out[f] = mean_n h[n][f]
// ---------------------------------------------------------------------------
__global__ __launch_bounds__(256) void mean_kernel(const float* __restrict__ h,
                                                   float* __restrict__ out, int n) {
    __shared__ float red[256];
    int f = threadIdx.x & 63;
    int w = threadIdx.x >> 6;
    int idx = blockIdx.x * 4 + w;
    int stride = gridDim.x * 4;
    float s = 0.f;
    for (int node = idx; node < n; node += stride) s += h[(size_t)node * 64 + f];
    red[threadIdx.x] = s;
    __syncthreads();
    if (w == 0) {
        float t = red[f] + red[64 + f] + red[128 + f] + red[192 + f];
        atomicAdd(&out[f], t / (float)n);
    }
}

extern "C" void kernel_launch(void* const* d_in, const int* in_sizes, int n_in,
                              void* d_out, int out_size, void* d_ws, size_t ws_size,
                              hipStream_t stream) {
    const float* x   = (const float*)d_in[0];
    const int*   ei  = (const int*)d_in[1];
    // d_in[2] = edge_attr (unused by reference, edge_dim=None)
    const float* W1  = (const float*)d_in[3];
    const float* as1 = (const float*)d_in[4];
    const float* ad1 = (const float*)d_in[5];
    const float* b1  = (const float*)d_in[6];
    const float* W2  = (const float*)d_in[7];
    const float* as2 = (const float*)d_in[8];
    const float* ad2 = (const float*)d_in[9];
    const float* b2  = (const float*)d_in[10];
    float* out = (float*)d_out;

    const int N = in_sizes[0] / 128;  // 100000
    const int E = in_sizes[1] / 2;    // 1600000
    const int T = E + N;              // edges incl. self-loops
    const int NB = (N + SCAN_ELEMS - 1) / SCAN_ELEMS;  // scan blocks (98) <= 256

    // Workspace carve-up (256B-aligned)
    size_t off = 0;
    char* base = (char*)d_ws;
    auto alloc = [&](size_t bytes) -> void* {
        void* p = base + off;
        off += (bytes + 255) & ~(size_t)255;
        return p;
    };
    int*   flag    = (int*)alloc(4);
    int*   deg     = (int*)alloc((size_t)N * 4);
    int*   ptr     = (int*)alloc(((size_t)N + 1) * 4);
    int*   cursor  = (int*)alloc((size_t)N * 4);
    int*   bsums   = (int*)alloc(256 * 4);
    int*   csr_src = (int*)alloc((size_t)T * 4);
    float* asrc    = (float*)alloc((size_t)N * 4);
    float* adst    = (float*)alloc((size_t)N * 4);
    float* bufA    = (float*)alloc((size_t)N * 64 * 4);
    float* bufB    = (float*)alloc((size_t)N * 64 * 4);
    (void)ws_size;

    // --- CSR build (shared by both layers) ---
    detect_kernel<<<1, 256, 0, stream>>>(ei, flag);
    hipMemsetAsync(deg, 0, (size_t)N * 4, stream);
    count_kernel<<<(T + 255) / 256, 256, 0, stream>>>(ei, flag, deg, E, N);
    scan1_kernel<<<NB, 256, 0, stream>>>(deg, bsums, N);
    scan2_kernel<<<1, 256, 0, stream>>>(bsums, NB);
    scan3_kernel<<<NB, 256, 0, stream>>>(deg, bsums, ptr, cursor, N, NB);
    scatter_kernel<<<(T + 255) / 256, 256, 0, stream>>>(ei, flag, cursor, csr_src, E, N);

    const int PGRID = (N + 63) / 64;

    // --- Layer 1: proj (x @ W1) + attention aggregate + ReLU ---
    proj_gemm<128><<<PGRID, 256, 0, stream>>>(x, W1, as1, ad1, bufA, asrc, adst, N);
    agg_kernel<<<(N * 64 + 255) / 256, 256, 0, stream>>>(ptr, csr_src, bufA, asrc, adst,
                                                         b1, bufB, N, 1);

    // --- Layer 2: proj (h @ W2) + attention aggregate ---
    proj_gemm<64><<<PGRID, 256, 0, stream>>>(bufB, W2, as2, ad2, bufA, asrc, adst, N);
    agg_kernel<<<(N * 64 + 255) / 256, 256, 0, stream>>>(ptr, csr_src, bufA, asrc, adst,
                                                         b2, bufB, N, 0);

    // --- Global mean pool ---
    hipMemsetAsync(out, 0, 64 * 4, stream);
    mean_kernel<<<256, 256, 0, stream>>>(bufB, out, N);
}

// Round 5
// 449.499 us; speedup vs baseline: 2.4122x; 1.2391x over previous
//
#include <hip/hip_runtime.h>
#include <hip/hip_bf16.h>
#include <cstdint>

#define NEG_SLOPE 0.2f
#define SCAN_ELEMS 1024   // elements per scan block (256 thr x 4)
#define BUCKET_SHIFT 9    // 512 nodes per bucket
#define CHUNK 8192        // edges per bucketing block

// ---------------------------------------------------------------------------
// int64-vs-int32 edge_index detection (odd words of src row all zero => i64).
// ---------------------------------------------------------------------------
__global__ __launch_bounds__(256) void detect_kernel(const int* __restrict__ ei,
                                                     int* __restrict__ flag) {
    __shared__ int red[256];
    int t = threadIdx.x;
    int v = 0;
    for (int i = t; i < 2048; i += 256) v |= ei[2 * i + 1];
    red[t] = v;
    __syncthreads();
    for (int off = 128; off; off >>= 1) {
        if (t < off) red[t] |= red[t + off];
        __syncthreads();
    }
    if (t == 0) *flag = (red[0] == 0) ? 1 : 0;
}

__device__ inline int get_ei(const int* ei, int is64, long idx) {
    return is64 ? ei[2 * idx] : ei[(int)idx];
}

// ---------------------------------------------------------------------------
// Counting-sort CSR build.
// p1: per-(block,chunk) LDS histogram over dst-buckets -> HH[bucket][blk]
// ---------------------------------------------------------------------------
__global__ __launch_bounds__(256) void p1_hist(const int* __restrict__ ei,
                                               const int* __restrict__ flag,
                                               int* __restrict__ HH,
                                               int E, int n, int nblk) {
    __shared__ int cnt[256];
    int tid = threadIdx.x;
    int nbuk = (n + (1 << BUCKET_SHIFT) - 1) >> BUCKET_SHIFT;  // <=256
    for (int b = tid; b < nbuk; b += 256) cnt[b] = 0;
    __syncthreads();
    int is64 = *flag;
    int total = E + n;
    int beg = blockIdx.x * CHUNK;
    int end = beg + CHUNK; if (end > total) end = total;
    for (int i = beg + tid; i < end; i += 256) {
        int d = (i < E) ? get_ei(ei, is64, (long)E + i) : (i - E);
        atomicAdd(&cnt[d >> BUCKET_SHIFT], 1);
    }
    __syncthreads();
    for (int b = tid; b < nbuk; b += 256) HH[b * nblk + blockIdx.x] = cnt[b];
}

// scan phase 1: per-block sums of an int array
__global__ __launch_bounds__(256) void scan1_kernel(const int* __restrict__ src,
                                                    int* __restrict__ bsums, int n) {
    int t = threadIdx.x;
    int i0 = blockIdx.x * SCAN_ELEMS + 4 * t;
    int4 v = make_int4(0, 0, 0, 0);
    if (i0 + 3 < n) v = *(const int4*)(src + i0);
    else {
        if (i0 + 0 < n) v.x = src[i0 + 0];
        if (i0 + 1 < n) v.y = src[i0 + 1];
        if (i0 + 2 < n) v.z = src[i0 + 2];
        if (i0 + 3 < n) v.w = src[i0 + 3];
    }
    int s = v.x + v.y + v.z + v.w;
#pragma unroll
    for (int off = 32; off; off >>= 1) s += __shfl_down(s, off);
    __shared__ int ws[4];
    if ((t & 63) == 0) ws[t >> 6] = s;
    __syncthreads();
    if (t == 0) bsums[blockIdx.x] = ws[0] + ws[1] + ws[2] + ws[3];
}

// scan phase 2: exclusive scan of <=256 block sums
__global__ __launch_bounds__(256) void scan2_kernel(int* __restrict__ bsums, int nb) {
    __shared__ int sh[256];
    int t = threadIdx.x;
    int v = (t < nb) ? bsums[t] : 0;
    sh[t] = v;
    __syncthreads();
    for (int off = 1; off < 256; off <<= 1) {
        int u = (t >= off) ? sh[t - off] : 0;
        __syncthreads();
        sh[t] += u;
        __syncthreads();
    }
    if (t < nb) bsums[t] = sh[t] - v;
}

// scan phase 3 (generic): out[i] = exclusive scan of src
__global__ __launch_bounds__(256) void scan3g_kernel(const int* __restrict__ src,
                                                     const int* __restrict__ bsums,
                                                     int* __restrict__ out, int n) {
    int b = blockIdx.x;
    int t = threadIdx.x;
    int i0 = b * SCAN_ELEMS + 4 * t;
    int4 v = make_int4(0, 0, 0, 0);
    if (i0 + 3 < n) v = *(const int4*)(src + i0);
    else {
        if (i0 + 0 < n) v.x = src[i0 + 0];
        if (i0 + 1 < n) v.y = src[i0 + 1];
        if (i0 + 2 < n) v.z = src[i0 + 2];
        if (i0 + 3 < n) v.w = src[i0 + 3];
    }
    int s0 = v.x, s1 = s0 + v.y, s2 = s1 + v.z, s3 = s2 + v.w;
    __shared__ int sh[256];
    sh[t] = s3;
    __syncthreads();
    for (int off = 1; off < 256; off <<= 1) {
        int u = (t >= off) ? sh[t - off] : 0;
        __syncthreads();
        sh[t] += u;
        __syncthreads();
    }
    int base = bsums[b] + sh[t] - s3;
    if (i0 + 0 < n) out[i0 + 0] = base;
    if (i0 + 1 < n) out[i0 + 1] = base + s0;
    if (i0 + 2 < n) out[i0 + 2] = base + s1;
    if (i0 + 3 < n) out[i0 + 3] = base + s2;
}

// p3: scatter edges into bucket-sorted int2 array using scanned offsets.
// Each (block,bucket) segment is contiguous -> near-coalesced writes.
__global__ __launch_bounds__(256) void p3_scatter(const int* __restrict__ ei,
                                                  const int* __restrict__ flag,
                                                  const int* __restrict__ scanHH,
                                                  int2* __restrict__ sorted,
                                                  int E, int n, int nblk) {
    __shared__ int base[256];
    __shared__ int cur[256];
    int tid = threadIdx.x;
    int nbuk = (n + (1 << BUCKET_SHIFT) - 1) >> BUCKET_SHIFT;
    for (int b = tid; b < nbuk; b += 256) {
        base[b] = scanHH[b * nblk + blockIdx.x];
        cur[b] = 0;
    }
    __syncthreads();
    int is64 = *flag;
    int total = E + n;
    int beg = blockIdx.x * CHUNK;
    int end = beg + CHUNK; if (end > total) end = total;
    for (int i = beg + tid; i < end; i += 256) {
        int s, d;
        if (i < E) {
            s = get_ei(ei, is64, i);
            d = get_ei(ei, is64, (long)E + i);
        } else {
            s = d = i - E;
        }
        int b = d >> BUCKET_SHIFT;
        int p = base[b] + atomicAdd(&cur[b], 1);
        sorted[p] = make_int2(s, d);
    }
}

// p4: one block per bucket. Per-node LDS histogram + scan -> ptr (coalesced);
// then scatter csr_src within the bucket's own window (single-CU locality).
__global__ __launch_bounds__(256) void p4_finalize(const int* __restrict__ scanHH,
                                                   const int2* __restrict__ sorted,
                                                   int* __restrict__ ptr,
                                                   int* __restrict__ csr_src,
                                                   int n, int nblk, int T) {
    int b = blockIdx.x;
    int nbuk = gridDim.x;
    int tid = threadIdx.x;
    int node0 = b << BUCKET_SHIFT;
    int nn = n - node0; if (nn > (1 << BUCKET_SHIFT)) nn = 1 << BUCKET_SHIFT;
    int beg = scanHH[b * nblk];
    int end = (b + 1 < nbuk) ? scanHH[(b + 1) * nblk] : T;

    __shared__ int cnt[512];
    __shared__ int pair[256];
    __shared__ int exc[512];
    cnt[tid] = 0; cnt[tid + 256] = 0;
    __syncthreads();
    for (int j = beg + tid; j < end; j += 256) {
        int2 e = sorted[j];
        atomicAdd(&cnt[e.y - node0], 1);
    }
    __syncthreads();
    // exclusive scan of cnt[0..511]: pair sums -> 256-scan -> expand
    int psum = cnt[2 * tid] + cnt[2 * tid + 1];
    pair[tid] = psum;
    __syncthreads();
    for (int off = 1; off < 256; off <<= 1) {
        int u = (tid >= off) ? pair[tid - off] : 0;
        __syncthreads();
        pair[tid] += u;
        __syncthreads();
    }
    int pexc = pair[tid] - psum;
    exc[2 * tid] = pexc;
    exc[2 * tid + 1] = pexc + cnt[2 * tid];
    __syncthreads();
    // write ptr (coalesced)
    for (int i = tid; i < nn; i += 256) ptr[node0 + i] = beg + exc[i];
    if (node0 + nn == n && tid == 0) ptr[n] = T;
    // cursors = exclusive offsets; reuse cnt
    cnt[tid] = exc[tid]; cnt[tid + 256] = exc[tid + 256];
    __syncthreads();
    for (int j = beg + tid; j < end; j += 256) {
        int2 e = sorted[j];
        int p = beg + atomicAdd(&cnt[e.y - node0], 1);
        csr_src[p] = e.x;
    }
}

// ---------------------------------------------------------------------------
// Projection as register-tiled GEMM: h = x @ W  [N,K] x [K,64] -> [N,64],
// fused a_src/a_dst dots. Block = 64 nodes x 64 feats; thread = 4x4 tile.
// ---------------------------------------------------------------------------
template <int K>
__global__ __launch_bounds__(256) void proj_gemm(const float* __restrict__ x,
                                                 const float* __restrict__ W,
                                                 const float* __restrict__ att_s,
                                                 const float* __restrict__ att_d,
                                                 float* __restrict__ h,
                                                 float* __restrict__ asrc,
                                                 float* __restrict__ adst, int n) {
    constexpr int KP = K + 4;
    constexpr int ROWF4 = K / 4;
    __shared__ float xs[64 * KP];
    int tid = threadIdx.x;
    int node0 = blockIdx.x * 64;

#pragma unroll
    for (int r = 0; r < (64 * ROWF4) / 256; ++r) {
        int f4 = tid + 256 * r;
        int row = f4 / ROWF4, c4 = f4 % ROWF4;
        float4 v = make_float4(0.f, 0.f, 0.f, 0.f);
        if (node0 + row < n) v = *(const float4*)(x + (size_t)(node0 + row) * K + 4 * c4);
        *(float4*)(xs + row * KP + 4 * c4) = v;
    }
    __syncthreads();

    int tf = tid & 15, tn = tid >> 4;
    float acc[4][4];
#pragma unroll
    for (int i = 0; i < 4; ++i)
#pragma unroll
        for (int j = 0; j < 4; ++j) acc[i][j] = 0.f;

    const float* wp = W + 4 * tf;
    const float* xp = xs + 4 * tn * KP;
#pragma unroll 4
    for (int k4 = 0; k4 < K / 4; ++k4) {
        float4 wv[4];
#pragma unroll
        for (int kk = 0; kk < 4; ++kk)
            wv[kk] = *(const float4*)(wp + (size_t)(4 * k4 + kk) * 64);
        float4 xv[4];
#pragma unroll
        for (int i = 0; i < 4; ++i)
            xv[i] = *(const float4*)(xp + i * KP + 4 * k4);
#pragma unroll
        for (int i = 0; i < 4; ++i) {
            const float xk[4] = {xv[i].x, xv[i].y, xv[i].z, xv[i].w};
#pragma unroll
            for (int kk = 0; kk < 4; ++kk) {
                const float* wf = (const float*)&wv[kk];
#pragma unroll
                for (int j = 0; j < 4; ++j) acc[i][j] = fmaf(xk[kk], wf[j], acc[i][j]);
            }
        }
    }

    float4 as = *(const float4*)(att_s + 4 * tf);
    float4 ad = *(const float4*)(att_d + 4 * tf);
#pragma unroll
    for (int i = 0; i < 4; ++i) {
        int node = node0 + 4 * tn + i;
        float ps = acc[i][0] * as.x + acc[i][1] * as.y + acc[i][2] * as.z + acc[i][3] * as.w;
        float pd = acc[i][0] * ad.x + acc[i][1] * ad.y + acc[i][2] * ad.z + acc[i][3] * ad.w;
#pragma unroll
        for (int off = 1; off < 16; off <<= 1) {
            ps += __shfl_xor(ps, off);
            pd += __shfl_xor(pd, off);
        }
        if (node < n) {
            *(float4*)(h + (size_t)node * 64 + 4 * tf) =
                make_float4(acc[i][0], acc[i][1], acc[i][2], acc[i][3]);
            if (tf == 0) { asrc[node] = ps; adst[node] = pd; }
        }
    }
}

// ---------------------------------------------------------------------------
// Fused edge softmax + aggregation. One wave per dst node, lane = feature.
// Softmax without max-subtraction (shift-invariant; |e| bounded ~12 here).
// Edge loop unrolled x8 for memory-level parallelism.
// ---------------------------------------------------------------------------
__global__ __launch_bounds__(256) void agg_kernel(const int* __restrict__ ptr,
                                                  const int* __restrict__ srcs,
                                                  const float* __restrict__ h,
                                                  const float* __restrict__ asrc,
                                                  const float* __restrict__ adst,
                                                  const float* __restrict__ bias,
                                                  float* __restrict__ out, int n, int do_relu) {
    int lane = threadIdx.x & 63;
    int node = (blockIdx.x * blockDim.x + threadIdx.x) >> 6;
    if (node >= n) return;
    int beg = ptr[node], end = ptr[node + 1];
    float ad = adst[node];
    float acc = 0.f, wsum = 0.f;
    int j = beg;
    for (; j + 8 <= end; j += 8) {
        int s[8];
#pragma unroll
        for (int u = 0; u < 8; ++u) s[u] = srcs[j + u];
        float ea[8];
#pragma unroll
        for (int u = 0; u < 8; ++u) ea[u] = asrc[s[u]];
        float hv[8];
#pragma unroll
        for (int u = 0; u < 8; ++u) hv[u] = h[(size_t)s[u] * 64 + lane];
#pragma unroll
        for (int u = 0; u < 8; ++u) {
            float e = ea[u] + ad;
            e = (e > 0.f) ? e : NEG_SLOPE * e;
            float w = __expf(e);
            wsum += w;
            acc = fmaf(w, hv[u], acc);
        }
    }
    for (; j < end; ++j) {
        int s = srcs[j];
        float e = asrc[s] + ad;
        e = (e > 0.f) ? e : NEG_SLOPE * e;
        float w = __expf(e);
        wsum += w;
        acc = fmaf(w, h[(size_t)s * 64 + lane], acc);
    }
    float o = acc / (wsum + 1e-16f) + bias[lane];
    if (do_relu) o = fmaxf(o, 0.f);
    out[(size_t)node * 64 + lane] = o;
}

// ---------------------------------------------------------------------------
// Global mean pool: out[f] = mean_n h[n][f]
// ---------------------------------------------------------------------------
__global__ __launch_bounds__(256) void mean_kernel(const float* __restrict__ h,
                                                   float* __restrict__ out, int n) {
    __shared__ float red[256];
    int f = threadIdx.x & 63;
    int w = threadIdx.x >> 6;
    int idx = blockIdx.x * 4 + w;
    int stride = gridDim.x * 4;
    float s = 0.f;
    for (int node = idx; node < n; node += stride) s += h[(size_t)node * 64 + f];
    red[threadIdx.x] = s;
    __syncthreads();
    if (w == 0) {
        float t = red[f] + red[64 + f] + red[128 + f] + red[192 + f];
        atomicAdd(&out[f], t / (float)n);
    }
}

extern "C" void kernel_launch(void* const* d_in, const int* in_sizes, int n_in,
                              void* d_out, int out_size, void* d_ws, size_t ws_size,
                              hipStream_t stream) {
    const float* x   = (const float*)d_in[0];
    const int*   ei  = (const int*)d_in[1];
    // d_in[2] = edge_attr (unused by reference, edge_dim=None)
    const float* W1  = (const float*)d_in[3];
    const float* as1 = (const float*)d_in[4];
    const float* ad1 = (const float*)d_in[5];
    const float* b1  = (const float*)d_in[6];
    const float* W2  = (const float*)d_in[7];
    const float* as2 = (const float*)d_in[8];
    const float* ad2 = (const float*)d_in[9];
    const float* b2  = (const float*)d_in[10];
    float* out = (float*)d_out;

    const int N = in_sizes[0] / 128;  // 100000
    const int E = in_sizes[1] / 2;    // 1600000
    const int T = E + N;              // edges incl. self-loops

    const int NBUK = (N + (1 << BUCKET_SHIFT) - 1) >> BUCKET_SHIFT;   // 196
    const int NBLK = (T + CHUNK - 1) / CHUNK;                          // 208
    const int NHH  = NBUK * NBLK;                                      // 40768
    const int NBS  = (NHH + SCAN_ELEMS - 1) / SCAN_ELEMS;              // 40

    // Workspace carve-up (256B-aligned)
    size_t off = 0;
    char* base = (char*)d_ws;
    auto alloc = [&](size_t bytes) -> void* {
        void* p = base + off;
        off += (bytes + 255) & ~(size_t)255;
        return p;
    };
    int*   flag    = (int*)alloc(4);
    int*   ptr     = (int*)alloc(((size_t)N + 1) * 4);
    int*   bsums   = (int*)alloc(256 * 4);
    int*   HH      = (int*)alloc((size_t)NHH * 4);
    int*   scanHH  = (int*)alloc((size_t)NHH * 4);
    int*   csr_src = (int*)alloc((size_t)T * 4);
    float* asrc    = (float*)alloc((size_t)N * 4);
    float* adst    = (float*)alloc((size_t)N * 4);
    float* bufA    = (float*)alloc((size_t)N * 64 * 4);
    float* bufB    = (float*)alloc((size_t)N * 64 * 4);
    int2*  sorted  = (int2*)bufA;   // overlay: dead before proj writes bufA
    (void)ws_size;

    // --- CSR build via counting sort (shared by both layers) ---
    detect_kernel<<<1, 256, 0, stream>>>(ei, flag);
    p1_hist<<<NBLK, 256, 0, stream>>>(ei, flag, HH, E, N, NBLK);
    scan1_kernel<<<NBS, 256, 0, stream>>>(HH, bsums, NHH);
    scan2_kernel<<<1, 256, 0, stream>>>(bsums, NBS);
    scan3g_kernel<<<NBS, 256, 0, stream>>>(HH, bsums, scanHH, NHH);
    p3_scatter<<<NBLK, 256, 0, stream>>>(ei, flag, scanHH, sorted, E, N, NBLK);
    p4_finalize<<<NBUK, 256, 0, stream>>>(scanHH, sorted, ptr, csr_src, N, NBLK, T);

    const int PGRID = (N + 63) / 64;

    // --- Layer 1: proj (x @ W1) + attention aggregate + ReLU ---
    proj_gemm<128><<<PGRID, 256, 0, stream>>>(x, W1, as1, ad1, bufA, asrc, adst, N);
    agg_kernel<<<(N * 64 + 255) / 256, 256, 0, stream>>>(ptr, csr_src, bufA, asrc, adst,
                                                         b1, bufB, N, 1);

    // --- Layer 2: proj (h @ W2) + attention aggregate ---
    proj_gemm<64><<<PGRID, 256, 0, stream>>>(bufB, W2, as2, ad2, bufA, asrc, adst, N);
    agg_kernel<<<(N * 64 + 255) / 256, 256, 0, stream>>>(ptr, csr_src, bufA, asrc, adst,
                                                         b2, bufB, N, 0);

    // --- Global mean pool ---
    hipMemsetAsync(out, 0, 64 * 4, stream);
    mean_kernel<<<256, 256, 0, stream>>>(bufB, out, N);
}

// Round 6
// 409.135 us; speedup vs baseline: 2.6502x; 1.0987x over previous
//
#include <hip/hip_runtime.h>
#include <hip/hip_bf16.h>
#include <cstdint>

#define NEG_SLOPE 0.2f
#define SCAN_ELEMS 1024   // elements per scan block (256 thr x 4)
#define BUCKET_SHIFT 9    // 512 nodes per bucket
#define CHUNK 8192        // edges per bucketing block

__device__ inline float bf2f(unsigned short u) {
    return __uint_as_float(((unsigned)u) << 16);
}
__device__ inline unsigned short f2bf(float f) {  // round-to-nearest-even
    unsigned xi = __float_as_uint(f);
    unsigned r = xi + 0x7fffu + ((xi >> 16) & 1u);
    return (unsigned short)(r >> 16);
}
__device__ inline int rl_i(int v, int l) { return __builtin_amdgcn_readlane(v, l); }
__device__ inline float rl_f(float v, int l) {
    return __int_as_float(__builtin_amdgcn_readlane(__float_as_int(v), l));
}

// ---------------------------------------------------------------------------
// int64-vs-int32 edge_index detection (odd words of src row all zero => i64).
// ---------------------------------------------------------------------------
__global__ __launch_bounds__(256) void detect_kernel(const int* __restrict__ ei,
                                                     int* __restrict__ flag) {
    __shared__ int red[256];
    int t = threadIdx.x;
    int v = 0;
    for (int i = t; i < 2048; i += 256) v |= ei[2 * i + 1];
    red[t] = v;
    __syncthreads();
    for (int off = 128; off; off >>= 1) {
        if (t < off) red[t] |= red[t + off];
        __syncthreads();
    }
    if (t == 0) *flag = (red[0] == 0) ? 1 : 0;
}

__device__ inline int get_ei(const int* ei, int is64, long idx) {
    return is64 ? ei[2 * idx] : ei[(int)idx];
}

// ---------------------------------------------------------------------------
// Counting-sort CSR build.
// p1: per-(block,chunk) LDS histogram over dst-buckets -> HH[bucket][blk]
// ---------------------------------------------------------------------------
__global__ __launch_bounds__(256) void p1_hist(const int* __restrict__ ei,
                                               const int* __restrict__ flag,
                                               int* __restrict__ HH,
                                               int E, int n, int nblk) {
    __shared__ int cnt[256];
    int tid = threadIdx.x;
    int nbuk = (n + (1 << BUCKET_SHIFT) - 1) >> BUCKET_SHIFT;  // <=256
    for (int b = tid; b < nbuk; b += 256) cnt[b] = 0;
    __syncthreads();
    int is64 = *flag;
    int total = E + n;
    int beg = blockIdx.x * CHUNK;
    int end = beg + CHUNK; if (end > total) end = total;
    for (int i = beg + tid; i < end; i += 256) {
        int d = (i < E) ? get_ei(ei, is64, (long)E + i) : (i - E);
        atomicAdd(&cnt[d >> BUCKET_SHIFT], 1);
    }
    __syncthreads();
    for (int b = tid; b < nbuk; b += 256) HH[b * nblk + blockIdx.x] = cnt[b];
}

// scan phase 1: per-block sums of an int array
__global__ __launch_bounds__(256) void scan1_kernel(const int* __restrict__ src,
                                                    int* __restrict__ bsums, int n) {
    int t = threadIdx.x;
    int i0 = blockIdx.x * SCAN_ELEMS + 4 * t;
    int4 v = make_int4(0, 0, 0, 0);
    if (i0 + 3 < n) v = *(const int4*)(src + i0);
    else {
        if (i0 + 0 < n) v.x = src[i0 + 0];
        if (i0 + 1 < n) v.y = src[i0 + 1];
        if (i0 + 2 < n) v.z = src[i0 + 2];
        if (i0 + 3 < n) v.w = src[i0 + 3];
    }
    int s = v.x + v.y + v.z + v.w;
#pragma unroll
    for (int off = 32; off; off >>= 1) s += __shfl_down(s, off);
    __shared__ int ws[4];
    if ((t & 63) == 0) ws[t >> 6] = s;
    __syncthreads();
    if (t == 0) bsums[blockIdx.x] = ws[0] + ws[1] + ws[2] + ws[3];
}

// scan phase 2: exclusive scan of <=256 block sums
__global__ __launch_bounds__(256) void scan2_kernel(int* __restrict__ bsums, int nb) {
    __shared__ int sh[256];
    int t = threadIdx.x;
    int v = (t < nb) ? bsums[t] : 0;
    sh[t] = v;
    __syncthreads();
    for (int off = 1; off < 256; off <<= 1) {
        int u = (t >= off) ? sh[t - off] : 0;
        __syncthreads();
        sh[t] += u;
        __syncthreads();
    }
    if (t < nb) bsums[t] = sh[t] - v;
}

// scan phase 3 (generic): out[i] = exclusive scan of src
__global__ __launch_bounds__(256) void scan3g_kernel(const int* __restrict__ src,
                                                     const int* __restrict__ bsums,
                                                     int* __restrict__ out, int n) {
    int b = blockIdx.x;
    int t = threadIdx.x;
    int i0 = b * SCAN_ELEMS + 4 * t;
    int4 v = make_int4(0, 0, 0, 0);
    if (i0 + 3 < n) v = *(const int4*)(src + i0);
    else {
        if (i0 + 0 < n) v.x = src[i0 + 0];
        if (i0 + 1 < n) v.y = src[i0 + 1];
        if (i0 + 2 < n) v.z = src[i0 + 2];
        if (i0 + 3 < n) v.w = src[i0 + 3];
    }
    int s0 = v.x, s1 = s0 + v.y, s2 = s1 + v.z, s3 = s2 + v.w;
    __shared__ int sh[256];
    sh[t] = s3;
    __syncthreads();
    for (int off = 1; off < 256; off <<= 1) {
        int u = (t >= off) ? sh[t - off] : 0;
        __syncthreads();
        sh[t] += u;
        __syncthreads();
    }
    int base = bsums[b] + sh[t] - s3;
    if (i0 + 0 < n) out[i0 + 0] = base;
    if (i0 + 1 < n) out[i0 + 1] = base + s0;
    if (i0 + 2 < n) out[i0 + 2] = base + s1;
    if (i0 + 3 < n) out[i0 + 3] = base + s2;
}

// p3: scatter edges into bucket-sorted int2 array using scanned offsets.
__global__ __launch_bounds__(256) void p3_scatter(const int* __restrict__ ei,
                                                  const int* __restrict__ flag,
                                                  const int* __restrict__ scanHH,
                                                  int2* __restrict__ sorted,
                                                  int E, int n, int nblk) {
    __shared__ int base[256];
    __shared__ int cur[256];
    int tid = threadIdx.x;
    int nbuk = (n + (1 << BUCKET_SHIFT) - 1) >> BUCKET_SHIFT;
    for (int b = tid; b < nbuk; b += 256) {
        base[b] = scanHH[b * nblk + blockIdx.x];
        cur[b] = 0;
    }
    __syncthreads();
    int is64 = *flag;
    int total = E + n;
    int beg = blockIdx.x * CHUNK;
    int end = beg + CHUNK; if (end > total) end = total;
    for (int i = beg + tid; i < end; i += 256) {
        int s, d;
        if (i < E) {
            s = get_ei(ei, is64, i);
            d = get_ei(ei, is64, (long)E + i);
        } else {
            s = d = i - E;
        }
        int b = d >> BUCKET_SHIFT;
        int p = base[b] + atomicAdd(&cur[b], 1);
        sorted[p] = make_int2(s, d);
    }
}

// p4: one block per bucket. Per-node LDS histogram + scan -> ptr (coalesced);
// then scatter csr_src within the bucket's own window.
__global__ __launch_bounds__(256) void p4_finalize(const int* __restrict__ scanHH,
                                                   const int2* __restrict__ sorted,
                                                   int* __restrict__ ptr,
                                                   int* __restrict__ csr_src,
                                                   int n, int nblk, int T) {
    int b = blockIdx.x;
    int nbuk = gridDim.x;
    int tid = threadIdx.x;
    int node0 = b << BUCKET_SHIFT;
    int nn = n - node0; if (nn > (1 << BUCKET_SHIFT)) nn = 1 << BUCKET_SHIFT;
    int beg = scanHH[b * nblk];
    int end = (b + 1 < nbuk) ? scanHH[(b + 1) * nblk] : T;

    __shared__ int cnt[512];
    __shared__ int pair[256];
    __shared__ int exc[512];
    cnt[tid] = 0; cnt[tid + 256] = 0;
    __syncthreads();
    for (int j = beg + tid; j < end; j += 256) {
        int2 e = sorted[j];
        atomicAdd(&cnt[e.y - node0], 1);
    }
    __syncthreads();
    int psum = cnt[2 * tid] + cnt[2 * tid + 1];
    pair[tid] = psum;
    __syncthreads();
    for (int off = 1; off < 256; off <<= 1) {
        int u = (tid >= off) ? pair[tid - off] : 0;
        __syncthreads();
        pair[tid] += u;
        __syncthreads();
    }
    int pexc = pair[tid] - psum;
    exc[2 * tid] = pexc;
    exc[2 * tid + 1] = pexc + cnt[2 * tid];
    __syncthreads();
    for (int i = tid; i < nn; i += 256) ptr[node0 + i] = beg + exc[i];
    if (node0 + nn == n && tid == 0) ptr[n] = T;
    cnt[tid] = exc[tid]; cnt[tid + 256] = exc[tid + 256];
    __syncthreads();
    for (int j = beg + tid; j < end; j += 256) {
        int2 e = sorted[j];
        int p = beg + atomicAdd(&cnt[e.y - node0], 1);
        csr_src[p] = e.x;
    }
}

// ---------------------------------------------------------------------------
// Projection as register-tiled GEMM. Emits h in bf16 (only the agg gather
// consumes h; asrc/adst are computed here from the exact fp32 accumulators).
// Block = 64 nodes x 64 feats. Thread (tn,tf) owns a 4x4 tile.
// ---------------------------------------------------------------------------
template <int K>
__global__ __launch_bounds__(256) void proj_gemm(const float* __restrict__ x,
                                                 const float* __restrict__ W,
                                                 const float* __restrict__ att_s,
                                                 const float* __restrict__ att_d,
                                                 unsigned short* __restrict__ h2,
                                                 float* __restrict__ asrc,
                                                 float* __restrict__ adst, int n) {
    constexpr int KP = K + 4;
    constexpr int ROWF4 = K / 4;
    __shared__ float xs[64 * KP];
    int tid = threadIdx.x;
    int node0 = blockIdx.x * 64;

#pragma unroll
    for (int r = 0; r < (64 * ROWF4) / 256; ++r) {
        int f4 = tid + 256 * r;
        int row = f4 / ROWF4, c4 = f4 % ROWF4;
        float4 v = make_float4(0.f, 0.f, 0.f, 0.f);
        if (node0 + row < n) v = *(const float4*)(x + (size_t)(node0 + row) * K + 4 * c4);
        *(float4*)(xs + row * KP + 4 * c4) = v;
    }
    __syncthreads();

    int tf = tid & 15, tn = tid >> 4;
    float acc[4][4];
#pragma unroll
    for (int i = 0; i < 4; ++i)
#pragma unroll
        for (int j = 0; j < 4; ++j) acc[i][j] = 0.f;

    const float* wp = W + 4 * tf;
    const float* xp = xs + 4 * tn * KP;
#pragma unroll 4
    for (int k4 = 0; k4 < K / 4; ++k4) {
        float4 wv[4];
#pragma unroll
        for (int kk = 0; kk < 4; ++kk)
            wv[kk] = *(const float4*)(wp + (size_t)(4 * k4 + kk) * 64);
        float4 xv[4];
#pragma unroll
        for (int i = 0; i < 4; ++i)
            xv[i] = *(const float4*)(xp + i * KP + 4 * k4);
#pragma unroll
        for (int i = 0; i < 4; ++i) {
            const float xk[4] = {xv[i].x, xv[i].y, xv[i].z, xv[i].w};
#pragma unroll
            for (int kk = 0; kk < 4; ++kk) {
                const float* wf = (const float*)&wv[kk];
#pragma unroll
                for (int j = 0; j < 4; ++j) acc[i][j] = fmaf(xk[kk], wf[j], acc[i][j]);
            }
        }
    }

    float4 as = *(const float4*)(att_s + 4 * tf);
    float4 ad = *(const float4*)(att_d + 4 * tf);
#pragma unroll
    for (int i = 0; i < 4; ++i) {
        int node = node0 + 4 * tn + i;
        float ps = acc[i][0] * as.x + acc[i][1] * as.y + acc[i][2] * as.z + acc[i][3] * as.w;
        float pd = acc[i][0] * ad.x + acc[i][1] * ad.y + acc[i][2] * ad.z + acc[i][3] * ad.w;
#pragma unroll
        for (int off = 1; off < 16; off <<= 1) {
            ps += __shfl_xor(ps, off);
            pd += __shfl_xor(pd, off);
        }
        if (node < n) {
            ushort4 u;
            u.x = f2bf(acc[i][0]); u.y = f2bf(acc[i][1]);
            u.z = f2bf(acc[i][2]); u.w = f2bf(acc[i][3]);
            *(ushort4*)(h2 + (size_t)node * 64 + 4 * tf) = u;
            if (tf == 0) { asrc[node] = ps; adst[node] = pd; }
        }
    }
}

// ---------------------------------------------------------------------------
// Fused edge softmax + aggregation. One wave per dst node, lane = feature.
// Per 64-edge batch: lane i computes w for edge i (ONE exp per edge, not 64);
// then a readlane-broadcast loop does only fma(w_j, bf16(h2[s_j][lane])).
// Softmax without max-subtraction (shift-invariant; |e| bounded ~12 here).
// ---------------------------------------------------------------------------
__global__ __launch_bounds__(256) void agg_kernel(const int* __restrict__ ptr,
                                                  const int* __restrict__ srcs,
                                                  const unsigned short* __restrict__ h2,
                                                  const float* __restrict__ asrc,
                                                  const float* __restrict__ adst,
                                                  const float* __restrict__ bias,
                                                  float* __restrict__ out, int n, int do_relu) {
    int lane = threadIdx.x & 63;
    int node = (blockIdx.x * blockDim.x + threadIdx.x) >> 6;
    if (node >= n) return;
    int beg = ptr[node], end = ptr[node + 1];
    float ad = adst[node];
    float acc = 0.f, wsum_l = 0.f;
    for (int b = beg; b < end; b += 64) {
        int blen = end - b; if (blen > 64) blen = 64;
        int sv = 0; float wv = 0.f;
        if (lane < blen) {
            sv = srcs[b + lane];                 // coalesced
            float e = asrc[sv] + ad;             // L2-resident 4B gather
            e = (e > 0.f) ? e : NEG_SLOPE * e;
            wv = __expf(e);
        }
        wsum_l += wv;
        int j = 0;
        for (; j + 4 <= blen; j += 4) {
            int s0 = rl_i(sv, j + 0), s1 = rl_i(sv, j + 1);
            int s2 = rl_i(sv, j + 2), s3 = rl_i(sv, j + 3);
            float w0 = rl_f(wv, j + 0), w1 = rl_f(wv, j + 1);
            float w2 = rl_f(wv, j + 2), w3 = rl_f(wv, j + 3);
            float g0 = bf2f(h2[(size_t)s0 * 64 + lane]);
            float g1 = bf2f(h2[(size_t)s1 * 64 + lane]);
            float g2 = bf2f(h2[(size_t)s2 * 64 + lane]);
            float g3 = bf2f(h2[(size_t)s3 * 64 + lane]);
            acc = fmaf(w0, g0, acc);
            acc = fmaf(w1, g1, acc);
            acc = fmaf(w2, g2, acc);
            acc = fmaf(w3, g3, acc);
        }
        for (; j < blen; ++j) {
            int s0 = rl_i(sv, j);
            float w0 = rl_f(wv, j);
            acc = fmaf(w0, bf2f(h2[(size_t)s0 * 64 + lane]), acc);
        }
    }
#pragma unroll
    for (int off = 32; off; off >>= 1) wsum_l += __shfl_xor(wsum_l, off);
    float o = acc / (wsum_l + 1e-16f) + bias[lane];
    if (do_relu) o = fmaxf(o, 0.f);
    out[(size_t)node * 64 + lane] = o;
}

// ---------------------------------------------------------------------------
// Global mean pool: out[f] = mean_n h[n][f]
// ---------------------------------------------------------------------------
__global__ __launch_bounds__(256) void mean_kernel(const float* __restrict__ h,
                                                   float* __restrict__ out, int n) {
    __shared__ float red[256];
    int f = threadIdx.x & 63;
    int w = threadIdx.x >> 6;
    int idx = blockIdx.x * 4 + w;
    int stride = gridDim.x * 4;
    float s = 0.f;
    for (int node = idx; node < n; node += stride) s += h[(size_t)node * 64 + f];
    red[threadIdx.x] = s;
    __syncthreads();
    if (w == 0) {
        float t = red[f] + red[64 + f] + red[128 + f] + red[192 + f];
        atomicAdd(&out[f], t / (float)n);
    }
}

extern "C" void kernel_launch(void* const* d_in, const int* in_sizes, int n_in,
                              void* d_out, int out_size, void* d_ws, size_t ws_size,
                              hipStream_t stream) {
    const float* x   = (const float*)d_in[0];
    const int*   ei  = (const int*)d_in[1];
    // d_in[2] = edge_attr (unused by reference, edge_dim=None)
    const float* W1  = (const float*)d_in[3];
    const float* as1 = (const float*)d_in[4];
    const float* ad1 = (const float*)d_in[5];
    const float* b1  = (const float*)d_in[6];
    const float* W2  = (const float*)d_in[7];
    const float* as2 = (const float*)d_in[8];
    const float* ad2 = (const float*)d_in[9];
    const float* b2  = (const float*)d_in[10];
    float* out = (float*)d_out;

    const int N = in_sizes[0] / 128;  // 100000
    const int E = in_sizes[1] / 2;    // 1600000
    const int T = E + N;              // edges incl. self-loops

    const int NBUK = (N + (1 << BUCKET_SHIFT) - 1) >> BUCKET_SHIFT;   // 196
    const int NBLK = (T + CHUNK - 1) / CHUNK;                          // 208
    const int NHH  = NBUK * NBLK;
    const int NBS  = (NHH + SCAN_ELEMS - 1) / SCAN_ELEMS;

    // Workspace carve-up (256B-aligned)
    size_t off = 0;
    char* base = (char*)d_ws;
    auto alloc = [&](size_t bytes) -> void* {
        void* p = base + off;
        off += (bytes + 255) & ~(size_t)255;
        return p;
    };
    int*   flag    = (int*)alloc(4);
    int*   ptr     = (int*)alloc(((size_t)N + 1) * 4);
    int*   bsums   = (int*)alloc(256 * 4);
    int*   HH      = (int*)alloc((size_t)NHH * 4);
    int*   scanHH  = (int*)alloc((size_t)NHH * 4);
    int*   csr_src = (int*)alloc((size_t)T * 4);
    float* asrc    = (float*)alloc((size_t)N * 4);
    float* adst    = (float*)alloc((size_t)N * 4);
    unsigned short* h2 = (unsigned short*)alloc((size_t)N * 64 * 2);
    float* bufA    = (float*)alloc((size_t)N * 64 * 4);
    float* bufB    = (float*)alloc((size_t)N * 64 * 4);
    int2*  sorted  = (int2*)bufB;   // overlay: dead before agg1 writes bufB
    (void)ws_size;

    // --- CSR build via counting sort (shared by both layers) ---
    detect_kernel<<<1, 256, 0, stream>>>(ei, flag);
    p1_hist<<<NBLK, 256, 0, stream>>>(ei, flag, HH, E, N, NBLK);
    scan1_kernel<<<NBS, 256, 0, stream>>>(HH, bsums, NHH);
    scan2_kernel<<<1, 256, 0, stream>>>(bsums, NBS);
    scan3g_kernel<<<NBS, 256, 0, stream>>>(HH, bsums, scanHH, NHH);
    p3_scatter<<<NBLK, 256, 0, stream>>>(ei, flag, scanHH, sorted, E, N, NBLK);
    p4_finalize<<<NBUK, 256, 0, stream>>>(scanHH, sorted, ptr, csr_src, N, NBLK, T);

    const int PGRID = (N + 63) / 64;

    // --- Layer 1: proj (x @ W1) -> bf16 h2 + attention aggregate + ReLU ---
    proj_gemm<128><<<PGRID, 256, 0, stream>>>(x, W1, as1, ad1, h2, asrc, adst, N);
    agg_kernel<<<(N * 64 + 255) / 256, 256, 0, stream>>>(ptr, csr_src, h2, asrc, adst,
                                                         b1, bufB, N, 1);

    // --- Layer 2: proj (h @ W2) -> bf16 h2 + attention aggregate ---
    proj_gemm<64><<<PGRID, 256, 0, stream>>>(bufB, W2, as2, ad2, h2, asrc, adst, N);
    agg_kernel<<<(N * 64 + 255) / 256, 256, 0, stream>>>(ptr, csr_src, h2, asrc, adst,
                                                         b2, bufA, N, 0);

    // --- Global mean pool ---
    hipMemsetAsync(out, 0, 64 * 4, stream);
    mean_kernel<<<256, 256, 0, stream>>>(bufA, out, N);
}

// Round 7
// 399.937 us; speedup vs baseline: 2.7111x; 1.0230x over previous
//
#include <hip/hip_runtime.h>
#include <hip/hip_bf16.h>
#include <cstdint>

#define NEG_SLOPE 0.2f
#define SCAN_ELEMS 1024   // elements per scan block (256 thr x 4)
#define BUCKET_SHIFT 9    // 512 nodes per bucket
#define CHUNK 8192        // edges per bucketing block

__device__ inline unsigned short f2bf(float f) {  // round-to-nearest-even
    unsigned xi = __float_as_uint(f);
    unsigned r = xi + 0x7fffu + ((xi >> 16) & 1u);
    return (unsigned short)(r >> 16);
}

// ---------------------------------------------------------------------------
// int64-vs-int32 edge_index detection (odd words of src row all zero => i64).
// ---------------------------------------------------------------------------
__global__ __launch_bounds__(256) void detect_kernel(const int* __restrict__ ei,
                                                     int* __restrict__ flag) {
    __shared__ int red[256];
    int t = threadIdx.x;
    int v = 0;
    for (int i = t; i < 2048; i += 256) v |= ei[2 * i + 1];
    red[t] = v;
    __syncthreads();
    for (int off = 128; off; off >>= 1) {
        if (t < off) red[t] |= red[t + off];
        __syncthreads();
    }
    if (t == 0) *flag = (red[0] == 0) ? 1 : 0;
}

__device__ inline int get_ei(const int* ei, int is64, long idx) {
    return is64 ? ei[2 * idx] : ei[(int)idx];
}

// ---------------------------------------------------------------------------
// Counting-sort CSR build.
// p1: per-(block,chunk) LDS histogram over dst-buckets -> HH[bucket][blk]
// ---------------------------------------------------------------------------
__global__ __launch_bounds__(256) void p1_hist(const int* __restrict__ ei,
                                               const int* __restrict__ flag,
                                               int* __restrict__ HH,
                                               int E, int n, int nblk) {
    __shared__ int cnt[256];
    int tid = threadIdx.x;
    int nbuk = (n + (1 << BUCKET_SHIFT) - 1) >> BUCKET_SHIFT;  // <=256
    for (int b = tid; b < nbuk; b += 256) cnt[b] = 0;
    __syncthreads();
    int is64 = *flag;
    int total = E + n;
    int beg = blockIdx.x * CHUNK;
    int end = beg + CHUNK; if (end > total) end = total;
    for (int i = beg + tid; i < end; i += 256) {
        int d = (i < E) ? get_ei(ei, is64, (long)E + i) : (i - E);
        atomicAdd(&cnt[d >> BUCKET_SHIFT], 1);
    }
    __syncthreads();
    for (int b = tid; b < nbuk; b += 256) HH[b * nblk + blockIdx.x] = cnt[b];
}

// scan phase 1: per-block sums of an int array
__global__ __launch_bounds__(256) void scan1_kernel(const int* __restrict__ src,
                                                    int* __restrict__ bsums, int n) {
    int t = threadIdx.x;
    int i0 = blockIdx.x * SCAN_ELEMS + 4 * t;
    int4 v = make_int4(0, 0, 0, 0);
    if (i0 + 3 < n) v = *(const int4*)(src + i0);
    else {
        if (i0 + 0 < n) v.x = src[i0 + 0];
        if (i0 + 1 < n) v.y = src[i0 + 1];
        if (i0 + 2 < n) v.z = src[i0 + 2];
        if (i0 + 3 < n) v.w = src[i0 + 3];
    }
    int s = v.x + v.y + v.z + v.w;
#pragma unroll
    for (int off = 32; off; off >>= 1) s += __shfl_down(s, off);
    __shared__ int ws[4];
    if ((t & 63) == 0) ws[t >> 6] = s;
    __syncthreads();
    if (t == 0) bsums[blockIdx.x] = ws[0] + ws[1] + ws[2] + ws[3];
}

// scan phase 2: exclusive scan of <=256 block sums
__global__ __launch_bounds__(256) void scan2_kernel(int* __restrict__ bsums, int nb) {
    __shared__ int sh[256];
    int t = threadIdx.x;
    int v = (t < nb) ? bsums[t] : 0;
    sh[t] = v;
    __syncthreads();
    for (int off = 1; off < 256; off <<= 1) {
        int u = (t >= off) ? sh[t - off] : 0;
        __syncthreads();
        sh[t] += u;
        __syncthreads();
    }
    if (t < nb) bsums[t] = sh[t] - v;
}

// scan phase 3 (generic): out[i] = exclusive scan of src
__global__ __launch_bounds__(256) void scan3g_kernel(const int* __restrict__ src,
                                                     const int* __restrict__ bsums,
                                                     int* __restrict__ out, int n) {
    int b = blockIdx.x;
    int t = threadIdx.x;
    int i0 = b * SCAN_ELEMS + 4 * t;
    int4 v = make_int4(0, 0, 0, 0);
    if (i0 + 3 < n) v = *(const int4*)(src + i0);
    else {
        if (i0 + 0 < n) v.x = src[i0 + 0];
        if (i0 + 1 < n) v.y = src[i0 + 1];
        if (i0 + 2 < n) v.z = src[i0 + 2];
        if (i0 + 3 < n) v.w = src[i0 + 3];
    }
    int s0 = v.x, s1 = s0 + v.y, s2 = s1 + v.z, s3 = s2 + v.w;
    __shared__ int sh[256];
    sh[t] = s3;
    __syncthreads();
    for (int off = 1; off < 256; off <<= 1) {
        int u = (t >= off) ? sh[t - off] : 0;
        __syncthreads();
        sh[t] += u;
        __syncthreads();
    }
    int base = bsums[b] + sh[t] - s3;
    if (i0 + 0 < n) out[i0 + 0] = base;
    if (i0 + 1 < n) out[i0 + 1] = base + s0;
    if (i0 + 2 < n) out[i0 + 2] = base + s1;
    if (i0 + 3 < n) out[i0 + 3] = base + s2;
}

// p3: scatter edges into bucket-sorted PACKED array (s<<9 | d&511).
__global__ __launch_bounds__(256) void p3_scatter(const int* __restrict__ ei,
                                                  const int* __restrict__ flag,
                                                  const int* __restrict__ scanHH,
                                                  int* __restrict__ sorted,
                                                  int E, int n, int nblk) {
    __shared__ int base[256];
    __shared__ int cur[256];
    int tid = threadIdx.x;
    int nbuk = (n + (1 << BUCKET_SHIFT) - 1) >> BUCKET_SHIFT;
    for (int b = tid; b < nbuk; b += 256) {
        base[b] = scanHH[b * nblk + blockIdx.x];
        cur[b] = 0;
    }
    __syncthreads();
    int is64 = *flag;
    int total = E + n;
    int beg = blockIdx.x * CHUNK;
    int end = beg + CHUNK; if (end > total) end = total;
    for (int i = beg + tid; i < end; i += 256) {
        int s, d;
        if (i < E) {
            s = get_ei(ei, is64, i);
            d = get_ei(ei, is64, (long)E + i);
        } else {
            s = d = i - E;
        }
        int b = d >> BUCKET_SHIFT;
        int p = base[b] + atomicAdd(&cur[b], 1);
        sorted[p] = (s << BUCKET_SHIFT) | (d & ((1 << BUCKET_SHIFT) - 1));
    }
}

// p4: one block per bucket. Per-node LDS histogram + scan -> ptr (coalesced);
// then scatter csr_src within the bucket's own window.
__global__ __launch_bounds__(256) void p4_finalize(const int* __restrict__ scanHH,
                                                   const int* __restrict__ sorted,
                                                   int* __restrict__ ptr,
                                                   int* __restrict__ csr_src,
                                                   int n, int nblk, int T) {
    int b = blockIdx.x;
    int nbuk = gridDim.x;
    int tid = threadIdx.x;
    int node0 = b << BUCKET_SHIFT;
    int nn = n - node0; if (nn > (1 << BUCKET_SHIFT)) nn = 1 << BUCKET_SHIFT;
    int beg = scanHH[b * nblk];
    int end = (b + 1 < nbuk) ? scanHH[(b + 1) * nblk] : T;

    __shared__ int cnt[512];
    __shared__ int pair[256];
    __shared__ int exc[512];
    cnt[tid] = 0; cnt[tid + 256] = 0;
    __syncthreads();
    for (int j = beg + tid; j < end; j += 256) {
        int v = sorted[j];
        atomicAdd(&cnt[v & ((1 << BUCKET_SHIFT) - 1)], 1);
    }
    __syncthreads();
    int psum = cnt[2 * tid] + cnt[2 * tid + 1];
    pair[tid] = psum;
    __syncthreads();
    for (int off = 1; off < 256; off <<= 1) {
        int u = (tid >= off) ? pair[tid - off] : 0;
        __syncthreads();
        pair[tid] += u;
        __syncthreads();
    }
    int pexc = pair[tid] - psum;
    exc[2 * tid] = pexc;
    exc[2 * tid + 1] = pexc + cnt[2 * tid];
    __syncthreads();
    for (int i = tid; i < nn; i += 256) ptr[node0 + i] = beg + exc[i];
    if (node0 + nn == n && tid == 0) ptr[n] = T;
    cnt[tid] = exc[tid]; cnt[tid + 256] = exc[tid + 256];
    __syncthreads();
    for (int j = beg + tid; j < end; j += 256) {
        int v = sorted[j];
        int p = beg + atomicAdd(&cnt[v & ((1 << BUCKET_SHIFT) - 1)], 1);
        csr_src[p] = ((unsigned)v) >> BUCKET_SHIFT;
    }
}

// ---------------------------------------------------------------------------
// Projection as register-tiled GEMM. Emits h in bf16 (only the agg gather
// consumes h; asrc/adst are computed here from the exact fp32 accumulators).
// ---------------------------------------------------------------------------
template <int K>
__global__ __launch_bounds__(256) void proj_gemm(const float* __restrict__ x,
                                                 const float* __restrict__ W,
                                                 const float* __restrict__ att_s,
                                                 const float* __restrict__ att_d,
                                                 unsigned short* __restrict__ h2,
                                                 float* __restrict__ asrc,
                                                 float* __restrict__ adst, int n) {
    constexpr int KP = K + 4;
    constexpr int ROWF4 = K / 4;
    __shared__ float xs[64 * KP];
    int tid = threadIdx.x;
    int node0 = blockIdx.x * 64;

#pragma unroll
    for (int r = 0; r < (64 * ROWF4) / 256; ++r) {
        int f4 = tid + 256 * r;
        int row = f4 / ROWF4, c4 = f4 % ROWF4;
        float4 v = make_float4(0.f, 0.f, 0.f, 0.f);
        if (node0 + row < n) v = *(const float4*)(x + (size_t)(node0 + row) * K + 4 * c4);
        *(float4*)(xs + row * KP + 4 * c4) = v;
    }
    __syncthreads();

    int tf = tid & 15, tn = tid >> 4;
    float acc[4][4];
#pragma unroll
    for (int i = 0; i < 4; ++i)
#pragma unroll
        for (int j = 0; j < 4; ++j) acc[i][j] = 0.f;

    const float* wp = W + 4 * tf;
    const float* xp = xs + 4 * tn * KP;
#pragma unroll 4
    for (int k4 = 0; k4 < K / 4; ++k4) {
        float4 wv[4];
#pragma unroll
        for (int kk = 0; kk < 4; ++kk)
            wv[kk] = *(const float4*)(wp + (size_t)(4 * k4 + kk) * 64);
        float4 xv[4];
#pragma unroll
        for (int i = 0; i < 4; ++i)
            xv[i] = *(const float4*)(xp + i * KP + 4 * k4);
#pragma unroll
        for (int i = 0; i < 4; ++i) {
            const float xk[4] = {xv[i].x, xv[i].y, xv[i].z, xv[i].w};
#pragma unroll
            for (int kk = 0; kk < 4; ++kk) {
                const float* wf = (const float*)&wv[kk];
#pragma unroll
                for (int j = 0; j < 4; ++j) acc[i][j] = fmaf(xk[kk], wf[j], acc[i][j]);
            }
        }
    }

    float4 as = *(const float4*)(att_s + 4 * tf);
    float4 ad = *(const float4*)(att_d + 4 * tf);
#pragma unroll
    for (int i = 0; i < 4; ++i) {
        int node = node0 + 4 * tn + i;
        float ps = acc[i][0] * as.x + acc[i][1] * as.y + acc[i][2] * as.z + acc[i][3] * as.w;
        float pd = acc[i][0] * ad.x + acc[i][1] * ad.y + acc[i][2] * ad.z + acc[i][3] * ad.w;
#pragma unroll
        for (int off = 1; off < 16; off <<= 1) {
            ps += __shfl_xor(ps, off);
            pd += __shfl_xor(pd, off);
        }
        if (node < n) {
            ushort4 u;
            u.x = f2bf(acc[i][0]); u.y = f2bf(acc[i][1]);
            u.z = f2bf(acc[i][2]); u.w = f2bf(acc[i][3]);
            *(ushort4*)(h2 + (size_t)node * 64 + 4 * tf) = u;
            if (tf == 0) { asrc[node] = ps; adst[node] = pd; }
        }
    }
}

// ---------------------------------------------------------------------------
// Fused edge softmax + aggregation, half-wave ushort2 scheme.
// One wave per node (grid-stride). Per 64-edge batch: lane i computes w for
// edge i (one exp/edge); ids+weights staged in per-wave LDS (intra-wave, no
// barrier). Then lanes 0-31 process even edges / 32-63 odd edges, each lane
// loading ushort2 = 2 bf16 feats (4 B/lane, 256 B per load inst). Cross-half
// combine via shfl_xor(32). FMEAN: accumulate global mean in-kernel.
// ---------------------------------------------------------------------------
template <bool FMEAN>
__global__ __launch_bounds__(256) void agg_kernel(const int* __restrict__ ptr,
                                                  const int* __restrict__ srcs,
                                                  const unsigned short* __restrict__ h2,
                                                  const float* __restrict__ asrc,
                                                  const float* __restrict__ adst,
                                                  const float* __restrict__ bias,
                                                  float* __restrict__ outrow,
                                                  float* __restrict__ outmean,
                                                  int n, int do_relu, float inv_n) {
    __shared__ int   sm_s[4][64];
    __shared__ float sm_w[4][64];
    __shared__ float red[256];
    int tid = threadIdx.x;
    int lane = tid & 63, wid = tid >> 6;
    int half = lane >> 5, fp = lane & 31;      // feature-pair index
    const char* h2b = (const char*)h2;
    unsigned fpo = (unsigned)fp << 2;          // byte offset of ushort2 in row
    float b0 = bias[2 * fp], b1 = bias[2 * fp + 1];
    float msum0 = 0.f, msum1 = 0.f;

    int gwave = (blockIdx.x * blockDim.x + tid) >> 6;
    int nwaves = (gridDim.x * blockDim.x) >> 6;
    for (int node = gwave; node < n; node += nwaves) {
        int beg = ptr[node], end = ptr[node + 1];
        float ad = adst[node];
        float acc0 = 0.f, acc1 = 0.f, wsum = 0.f;
        for (int b = beg; b < end; b += 64) {
            int blen = end - b; if (blen > 64) blen = 64;
            int sv = 0; float wv = 0.f;
            if (lane < blen) {
                sv = srcs[b + lane];             // coalesced
                float e = asrc[sv] + ad;         // L2-resident 4B gather
                e = (e > 0.f) ? e : NEG_SLOPE * e;
                wv = __expf(e);
            }
            wsum += wv;
            sm_s[wid][lane] = sv;
            sm_w[wid][lane] = wv;
            int npf = blen >> 1;                 // full edge-pairs
            int j = 0;
            for (; j + 4 <= npf; j += 4) {
                int e0 = 2 * j + half, e1 = e0 + 2, e2 = e0 + 4, e3 = e0 + 6;
                int s0 = sm_s[wid][e0], s1 = sm_s[wid][e1];
                int s2 = sm_s[wid][e2], s3 = sm_s[wid][e3];
                float w0 = sm_w[wid][e0], w1 = sm_w[wid][e1];
                float w2 = sm_w[wid][e2], w3 = sm_w[wid][e3];
                unsigned g0 = *(const unsigned*)(h2b + (((unsigned)s0 << 7) + fpo));
                unsigned g1 = *(const unsigned*)(h2b + (((unsigned)s1 << 7) + fpo));
                unsigned g2 = *(const unsigned*)(h2b + (((unsigned)s2 << 7) + fpo));
                unsigned g3 = *(const unsigned*)(h2b + (((unsigned)s3 << 7) + fpo));
                acc0 = fmaf(w0, __uint_as_float((g0 & 0xffffu) << 16), acc0);
                acc1 = fmaf(w0, __uint_as_float(g0 & 0xffff0000u), acc1);
                acc0 = fmaf(w1, __uint_as_float((g1 & 0xffffu) << 16), acc0);
                acc1 = fmaf(w1, __uint_as_float(g1 & 0xffff0000u), acc1);
                acc0 = fmaf(w2, __uint_as_float((g2 & 0xffffu) << 16), acc0);
                acc1 = fmaf(w2, __uint_as_float(g2 & 0xffff0000u), acc1);
                acc0 = fmaf(w3, __uint_as_float((g3 & 0xffffu) << 16), acc0);
                acc1 = fmaf(w3, __uint_as_float(g3 & 0xffff0000u), acc1);
            }
            for (; j < npf; ++j) {
                int e0 = 2 * j + half;
                int s0 = sm_s[wid][e0];
                float w0 = sm_w[wid][e0];
                unsigned g0 = *(const unsigned*)(h2b + (((unsigned)s0 << 7) + fpo));
                acc0 = fmaf(w0, __uint_as_float((g0 & 0xffffu) << 16), acc0);
                acc1 = fmaf(w0, __uint_as_float(g0 & 0xffff0000u), acc1);
            }
            if (blen & 1) {                      // last odd edge: half0 only
                int e0 = blen - 1;
                int s0 = sm_s[wid][e0];
                float w0 = (half == 0) ? sm_w[wid][e0] : 0.f;
                unsigned g0 = *(const unsigned*)(h2b + (((unsigned)s0 << 7) + fpo));
                acc0 = fmaf(w0, __uint_as_float((g0 & 0xffffu) << 16), acc0);
                acc1 = fmaf(w0, __uint_as_float(g0 & 0xffff0000u), acc1);
            }
        }
        acc0 += __shfl_xor(acc0, 32);            // combine even/odd halves
        acc1 += __shfl_xor(acc1, 32);
#pragma unroll
        for (int off = 32; off; off >>= 1) wsum += __shfl_xor(wsum, off);
        float inv = 1.f / (wsum + 1e-16f);
        float o0 = acc0 * inv + b0;
        float o1 = acc1 * inv + b1;
        if (!FMEAN) {
            if (do_relu) { o0 = fmaxf(o0, 0.f); o1 = fmaxf(o1, 0.f); }
            if (half == 0)
                *(float2*)(outrow + (size_t)node * 64 + 2 * fp) = make_float2(o0, o1);
        } else {
            if (half == 0) { msum0 += o0; msum1 += o1; }
        }
    }
    if (FMEAN) {
        if (half == 0) {
            red[wid * 64 + 2 * fp] = msum0;
            red[wid * 64 + 2 * fp + 1] = msum1;
        }
        __syncthreads();
        if (tid < 64) {
            float t = red[tid] + red[64 + tid] + red[128 + tid] + red[192 + tid];
            atomicAdd(&outmean[tid], t * inv_n);
        }
    }
}

extern "C" void kernel_launch(void* const* d_in, const int* in_sizes, int n_in,
                              void* d_out, int out_size, void* d_ws, size_t ws_size,
                              hipStream_t stream) {
    const float* x   = (const float*)d_in[0];
    const int*   ei  = (const int*)d_in[1];
    // d_in[2] = edge_attr (unused by reference, edge_dim=None)
    const float* W1  = (const float*)d_in[3];
    const float* as1 = (const float*)d_in[4];
    const float* ad1 = (const float*)d_in[5];
    const float* b1  = (const float*)d_in[6];
    const float* W2  = (const float*)d_in[7];
    const float* as2 = (const float*)d_in[8];
    const float* ad2 = (const float*)d_in[9];
    const float* b2  = (const float*)d_in[10];
    float* out = (float*)d_out;

    const int N = in_sizes[0] / 128;  // 100000
    const int E = in_sizes[1] / 2;    // 1600000
    const int T = E + N;              // edges incl. self-loops

    const int NBUK = (N + (1 << BUCKET_SHIFT) - 1) >> BUCKET_SHIFT;   // 196
    const int NBLK = (T + CHUNK - 1) / CHUNK;                          // 208
    const int NHH  = NBUK * NBLK;
    const int NBS  = (NHH + SCAN_ELEMS - 1) / SCAN_ELEMS;

    // Workspace carve-up (256B-aligned)
    size_t off = 0;
    char* base = (char*)d_ws;
    auto alloc = [&](size_t bytes) -> void* {
        void* p = base + off;
        off += (bytes + 255) & ~(size_t)255;
        return p;
    };
    int*   flag    = (int*)alloc(4);
    int*   ptr     = (int*)alloc(((size_t)N + 1) * 4);
    int*   bsums   = (int*)alloc(256 * 4);
    int*   HH      = (int*)alloc((size_t)NHH * 4);
    int*   scanHH  = (int*)alloc((size_t)NHH * 4);
    int*   csr_src = (int*)alloc((size_t)T * 4);
    float* asrc    = (float*)alloc((size_t)N * 4);
    float* adst    = (float*)alloc((size_t)N * 4);
    unsigned short* h2 = (unsigned short*)alloc((size_t)N * 64 * 2);
    float* bufB    = (float*)alloc((size_t)N * 64 * 4);
    int*   sorted  = (int*)bufB;    // overlay: dead before agg1 writes bufB
    (void)ws_size;

    // --- CSR build via counting sort (shared by both layers) ---
    detect_kernel<<<1, 256, 0, stream>>>(ei, flag);
    p1_hist<<<NBLK, 256, 0, stream>>>(ei, flag, HH, E, N, NBLK);
    scan1_kernel<<<NBS, 256, 0, stream>>>(HH, bsums, NHH);
    scan2_kernel<<<1, 256, 0, stream>>>(bsums, NBS);
    scan3g_kernel<<<NBS, 256, 0, stream>>>(HH, bsums, scanHH, NHH);
    p3_scatter<<<NBLK, 256, 0, stream>>>(ei, flag, scanHH, sorted, E, N, NBLK);
    p4_finalize<<<NBUK, 256, 0, stream>>>(scanHH, sorted, ptr, csr_src, N, NBLK, T);

    const int PGRID = (N + 63) / 64;

    // --- Layer 1: proj (x @ W1) -> bf16 h2 + attention aggregate + ReLU ---
    proj_gemm<128><<<PGRID, 256, 0, stream>>>(x, W1, as1, ad1, h2, asrc, adst, N);
    agg_kernel<false><<<(N + 3) / 4, 256, 0, stream>>>(ptr, csr_src, h2, asrc, adst,
                                                       b1, bufB, nullptr, N, 1, 0.f);

    // --- Layer 2: proj (h @ W2) -> bf16 h2 + attention aggregate + mean ---
    proj_gemm<64><<<PGRID, 256, 0, stream>>>(bufB, W2, as2, ad2, h2, asrc, adst, N);
    hipMemsetAsync(out, 0, 64 * 4, stream);
    agg_kernel<true><<<1024, 256, 0, stream>>>(ptr, csr_src, h2, asrc, adst,
                                               b2, nullptr, out, N, 0, 1.f / (float)N);
}